// Round 1
// baseline (1046.563 us; speedup 1.0000x reference)
//
#include <hip/hip_runtime.h>
#include <hip/hip_bf16.h>

// Problem constants
constexpr int Bb = 256;   // batch
constexpr int Nn = 512;   // nodes
constexpr int Dd = 512;   // model dim
constexpr int Hh = 8;     // heads
constexpr int Tt = 128;   // steps
#define NEGF (-1.0e9f)

typedef __attribute__((ext_vector_type(4))) float f32x4;
typedef __attribute__((ext_vector_type(8))) short bf16x8;     // MFMA a/b frag (8 bf16)
typedef __attribute__((ext_vector_type(8))) unsigned short u16x8;

__device__ __forceinline__ unsigned short f2bf(float f) {
  union { float f; unsigned u; } v; v.f = f;
  unsigned r = v.u + 0x7fffu + ((v.u >> 16) & 1u);   // RNE
  return (unsigned short)(r >> 16);
}

// ---------------- cast embeddings f32 -> bf16 ----------------
__global__ void cast_emb_k(const float* __restrict__ src, unsigned short* __restrict__ dst, int n8) {
  int i = blockIdx.x * 256 + threadIdx.x;
  if (i >= n8) return;
  const float4* s = (const float4*)src + (size_t)i * 2;
  float4 a = s[0], b = s[1];
  u16x8 o;
  o[0] = f2bf(a.x); o[1] = f2bf(a.y); o[2] = f2bf(a.z); o[3] = f2bf(a.w);
  o[4] = f2bf(b.x); o[5] = f2bf(b.y); o[6] = f2bf(b.z); o[7] = f2bf(b.w);
  ((u16x8*)dst)[i] = o;
}

// ---------------- transpose-cast 512x512 weight blocks to [n][k] bf16 ----------------
__global__ void cast_wt_k(const float* __restrict__ W0, const float* __restrict__ W1,
                          const float* __restrict__ W2, const float* __restrict__ W3,
                          const float* __restrict__ W4,
                          unsigned short* __restrict__ D0, unsigned short* __restrict__ D1,
                          unsigned short* __restrict__ D2, unsigned short* __restrict__ D3,
                          unsigned short* __restrict__ D4) {
  int mid = blockIdx.x >> 8;
  int tile = blockIdx.x & 255;
  const float* S = (mid == 0) ? W0 : (mid == 1) ? W1 : (mid == 2) ? W2 : (mid == 3) ? W3 : W4;
  unsigned short* Dst = (mid == 0) ? D0 : (mid == 1) ? D1 : (mid == 2) ? D2 : (mid == 3) ? D3 : D4;
  __shared__ float t[32][33];
  int r0 = (tile >> 4) * 32, c0 = (tile & 15) * 32;
  int tx = threadIdx.x & 31, ty = threadIdx.x >> 5;
#pragma unroll
  for (int yy = 0; yy < 4; ++yy) {
    int r = ty + yy * 8;
    t[r][tx] = S[(size_t)(r0 + r) * 512 + c0 + tx];
  }
  __syncthreads();
#pragma unroll
  for (int yy = 0; yy < 4; ++yy) {
    int c = ty + yy * 8;
    Dst[(size_t)(c0 + c) * 512 + r0 + tx] = f2bf(t[tx][c]);   // Dst[n][k] = W[k][n]
  }
}

// ---------------- Q_context = mge @ Wqc (f32) ----------------
__global__ void qc_k(const float* __restrict__ mge, const float* __restrict__ Wqc,
                     float* __restrict__ Qc) {
  int b = blockIdx.x;
  __shared__ float m[512];
  m[threadIdx.x] = mge[(size_t)b * 512 + threadIdx.x];
  m[threadIdx.x + 256] = mge[(size_t)b * 512 + threadIdx.x + 256];
  __syncthreads();
  float a0 = 0.f, a1 = 0.f;
  for (int k = 0; k < 512; ++k) {
    float mk = m[k];
    a0 += mk * Wqc[(size_t)k * 512 + threadIdx.x];
    a1 += mk * Wqc[(size_t)k * 512 + threadIdx.x + 256];
  }
  Qc[(size_t)b * 512 + threadIdx.x] = a0;
  Qc[(size_t)b * 512 + threadIdx.x + 256] = a1;
}

// ---------------- gather step-context rows (bf16) ----------------
__global__ void gather_k(const unsigned short* __restrict__ embB, const int* __restrict__ prev,
                         unsigned short* __restrict__ SC) {
  int row = blockIdx.x * 4 + (threadIdx.x >> 6);   // row = t*B + b
  int lane = threadIdx.x & 63;
  int t = row >> 8, b = row & 255;
  int pa = prev[t * Bb + b];
  const u16x8* s = (const u16x8*)(embB + (size_t)(b * 512 + pa) * 512) + lane;
  *((u16x8*)(SC + (size_t)row * 512) + lane) = *s;
}

// ---------------- GEMM C[M,512] = A[M,512] x BT[512,512]^T  (bf16 MFMA) ----------------
// MODE 0: f32 out, MODE 1: bf16 out, MODE 2: bf16 transposed out (Vt[b][d][n])
template <int MODE>
__global__ __launch_bounds__(256, 2)
void gemm_bt_k(const unsigned short* __restrict__ A, const unsigned short* __restrict__ BT,
               void* __restrict__ Cout, int MT) {
  __shared__ __align__(16) char lds[32768];   // A tile [128][64], B tile [128][64], swizzled
  int bid = blockIdx.x;
  int x = bid & 7;
  int i = bid >> 3;
  int per = MT >> 3;
  int nt = i & 3;
  int mt = x * per + (i >> 2);
  int m0 = mt * 128, n0 = nt * 128;
  int tid = threadIdx.x;
  int lane = tid & 63;
  int wid = tid >> 6;
  int wm = wid >> 1, wn = wid & 1;
  int l15 = lane & 15, l4 = lane >> 4;

  f32x4 acc[4][4] = {};

  for (int k0 = 0; k0 < 512; k0 += 64) {
    __syncthreads();
    // stage A (rows m0.., 64 k) and BT (rows n0.., 64 k), 16B/lane, XOR-swizzled LDS
#pragma unroll
    for (int c4 = 0; c4 < 4; ++c4) {
      int ch = tid + c4 * 256;
      int r = ch >> 3, cb = ch & 7;
      u16x8 v = *(const u16x8*)(A + (size_t)(m0 + r) * 512 + k0 + cb * 8);
      *(u16x8*)(lds + r * 128 + ((cb * 16) ^ ((r & 7) << 4))) = v;
    }
#pragma unroll
    for (int c4 = 0; c4 < 4; ++c4) {
      int ch = tid + c4 * 256;
      int r = ch >> 3, cb = ch & 7;
      u16x8 v = *(const u16x8*)(BT + (size_t)(n0 + r) * 512 + k0 + cb * 8);
      *(u16x8*)(lds + 16384 + r * 128 + ((cb * 16) ^ ((r & 7) << 4))) = v;
    }
    __syncthreads();
#pragma unroll
    for (int ks = 0; ks < 2; ++ks) {
      bf16x8 fa[4], fb[4];
#pragma unroll
      for (int ii = 0; ii < 4; ++ii) {
        int r = wm * 64 + ii * 16 + l15;
        int kb = ks * 64 + l4 * 16;
        fa[ii] = *(const bf16x8*)(lds + r * 128 + (kb ^ ((r & 7) << 4)));
      }
#pragma unroll
      for (int jj = 0; jj < 4; ++jj) {
        int r = wn * 64 + jj * 16 + l15;
        int kb = ks * 64 + l4 * 16;
        fb[jj] = *(const bf16x8*)(lds + 16384 + r * 128 + (kb ^ ((r & 7) << 4)));
      }
#pragma unroll
      for (int ii = 0; ii < 4; ++ii)
#pragma unroll
        for (int jj = 0; jj < 4; ++jj)
          acc[ii][jj] = __builtin_amdgcn_mfma_f32_16x16x32_bf16(fa[ii], fb[jj], acc[ii][jj], 0, 0, 0);
    }
  }

  if (MODE == 0) {
    float* C = (float*)Cout;
#pragma unroll
    for (int ii = 0; ii < 4; ++ii)
#pragma unroll
      for (int jj = 0; jj < 4; ++jj)
#pragma unroll
        for (int r = 0; r < 4; ++r) {
          int row = m0 + wm * 64 + ii * 16 + l4 * 4 + r;
          int col = n0 + wn * 64 + jj * 16 + l15;
          C[(size_t)row * 512 + col] = acc[ii][jj][r];
        }
  } else if (MODE == 1) {
    unsigned short* C = (unsigned short*)Cout;
#pragma unroll
    for (int ii = 0; ii < 4; ++ii)
#pragma unroll
      for (int jj = 0; jj < 4; ++jj)
#pragma unroll
        for (int r = 0; r < 4; ++r) {
          int row = m0 + wm * 64 + ii * 16 + l4 * 4 + r;
          int col = n0 + wn * 64 + jj * 16 + l15;
          C[(size_t)row * 512 + col] = f2bf(acc[ii][jj][r]);
        }
  } else {
    // transposed write: Vt[b][d][n], tile rows are (b,n), cols are d
    int bb = m0 >> 9, nn0 = m0 & 511, d0 = n0;
    unsigned short* C = (unsigned short*)Cout;
#pragma unroll
    for (int p = 0; p < 2; ++p) {
      __syncthreads();
      if (wn == p) {
#pragma unroll
        for (int ii = 0; ii < 4; ++ii)
#pragma unroll
          for (int jj = 0; jj < 4; ++jj)
#pragma unroll
            for (int r = 0; r < 4; ++r) {
              int d = jj * 16 + l15;                       // 0..63 within this pass
              int m = wm * 64 + ii * 16 + l4 * 4 + r;      // 0..127 (n within tile)
              *(unsigned short*)(lds + d * 272 + m * 2) = f2bf(acc[ii][jj][r]);
            }
      }
      __syncthreads();
      int dl = tid >> 2, seg = tid & 3;
      const char* sp = lds + dl * 272 + seg * 64;
      unsigned short* dp = C + (size_t)(bb * 512 + d0 + p * 64 + dl) * 512 + nn0 + seg * 32;
      *(u16x8*)(dp) = *(const u16x8*)(sp);
      *(u16x8*)(dp + 8) = *(const u16x8*)(sp + 16);
      *(u16x8*)(dp + 16) = *(const u16x8*)(sp + 32);
      *(u16x8*)(dp + 24) = *(const u16x8*)(sp + 48);
    }
  }
}

// ---------------- q fixup: Qb[b*T+t] = bf16((Qraw[t*B+b] + Qc[b] + (1-cap)*w_last) / 8) ----------------
__global__ void qfix_k(const float* __restrict__ Qraw, const float* __restrict__ Qc,
                       const float* __restrict__ Wqs, const float* __restrict__ cap,
                       unsigned short* __restrict__ Qb) {
  int r = blockIdx.x;            // t*B + b
  int t = r >> 8, b = r & 255;
  float rc = 1.0f - cap[r];
#pragma unroll
  for (int half = 0; half < 2; ++half) {
    int d = threadIdx.x + half * 256;
    float q = Qraw[(size_t)r * 512 + d] + Qc[(size_t)b * 512 + d] + rc * Wqs[512 * 512 + d];
    Qb[(size_t)(b * Tt + t) * 512 + d] = f2bf(q * 0.125f);   // fold 1/sqrt(64)
  }
}

// ---------------- fused MHA per (b, h, 32-row t-tile) ----------------
__global__ __launch_bounds__(256, 1)
void attn_k(const unsigned short* __restrict__ Qb, const unsigned short* __restrict__ Kb,
            const unsigned short* __restrict__ Vt, const int* __restrict__ mask,
            unsigned short* __restrict__ mhaB) {
  __shared__ __align__(16) float S[32 * 513];
  __shared__ __align__(16) unsigned short P[32 * 520];
  int bid = blockIdx.x;
  int x = bid & 7, i = bid >> 3;
  int b = x * 32 + (i >> 5);
  int h = (i >> 2) & 7;
  int tt = i & 3;
  int tid = threadIdx.x, lane = tid & 63, w = tid >> 6;
  int l15 = lane & 15, l4 = lane >> 4;

  // Q fragments (scale 1/8 already folded into Qb)
  bf16x8 aq[2][2];
#pragma unroll
  for (int ii = 0; ii < 2; ++ii)
#pragma unroll
    for (int kk = 0; kk < 2; ++kk) {
      int t = tt * 32 + ii * 16 + l15;
      aq[ii][kk] = *(const bf16x8*)(Qb + (size_t)(b * Tt + t) * 512 + h * 64 + kk * 32 + l4 * 8);
    }

  // S = Q K^T over this wave's 128-col n-chunk
  f32x4 acc[2][8] = {};
#pragma unroll
  for (int jj = 0; jj < 8; ++jj) {
    int n = w * 128 + jj * 16 + l15;
    const unsigned short* kp = Kb + (size_t)(b * 512 + n) * 512 + h * 64 + l4 * 8;
    bf16x8 kb0 = *(const bf16x8*)(kp);
    bf16x8 kb1 = *(const bf16x8*)(kp + 32);
#pragma unroll
    for (int ii = 0; ii < 2; ++ii) {
      acc[ii][jj] = __builtin_amdgcn_mfma_f32_16x16x32_bf16(aq[ii][0], kb0, acc[ii][jj], 0, 0, 0);
      acc[ii][jj] = __builtin_amdgcn_mfma_f32_16x16x32_bf16(aq[ii][1], kb1, acc[ii][jj], 0, 0, 0);
    }
  }
#pragma unroll
  for (int ii = 0; ii < 2; ++ii)
#pragma unroll
    for (int jj = 0; jj < 8; ++jj)
#pragma unroll
      for (int r = 0; r < 4; ++r)
        S[(ii * 16 + l4 * 4 + r) * 513 + w * 128 + jj * 16 + l15] = acc[ii][jj][r];
  __syncthreads();

  // masked softmax, one row per wave-iteration, write P (bf16, normalized)
#pragma unroll
  for (int rr = 0; rr < 8; ++rr) {
    int row = w * 8 + rr;
    int tg = tt * 32 + row;
    float v[8];
    float mx = -3.0e38f;
#pragma unroll
    for (int c8 = 0; c8 < 8; ++c8) {
      int c = lane + c8 * 64;
      float xv = S[row * 513 + c];
      int mv = mask[(size_t)tg * (Bb * Nn) + b * Nn + c];
      xv = mv ? NEGF : xv;
      v[c8] = xv;
      mx = fmaxf(mx, xv);
    }
#pragma unroll
    for (int off = 32; off >= 1; off >>= 1) mx = fmaxf(mx, __shfl_xor(mx, off));
    float sum = 0.f;
#pragma unroll
    for (int c8 = 0; c8 < 8; ++c8) { v[c8] = __expf(v[c8] - mx); sum += v[c8]; }
#pragma unroll
    for (int off = 32; off >= 1; off >>= 1) sum += __shfl_xor(sum, off);
    float inv = 1.0f / sum;
#pragma unroll
    for (int c8 = 0; c8 < 8; ++c8) P[row * 520 + lane + c8 * 64] = f2bf(v[c8] * inv);
  }
  __syncthreads();

  // PV: each wave accumulates its 128-wide k(n)-chunk, then cross-wave reduce
  f32x4 a2[2][4] = {};
  int k0 = w * 128;
#pragma unroll
  for (int ks = 0; ks < 4; ++ks) {
    bf16x8 pa[2];
#pragma unroll
    for (int ii = 0; ii < 2; ++ii)
      pa[ii] = *(const bf16x8*)(P + (ii * 16 + l15) * 520 + k0 + ks * 32 + l4 * 8);
#pragma unroll
    for (int jj = 0; jj < 4; ++jj) {
      bf16x8 vb = *(const bf16x8*)(Vt + (size_t)(b * 512 + h * 64 + jj * 16 + l15) * 512 + k0 + ks * 32 + l4 * 8);
#pragma unroll
      for (int ii = 0; ii < 2; ++ii)
        a2[ii][jj] = __builtin_amdgcn_mfma_f32_16x16x32_bf16(pa[ii], vb, a2[ii][jj], 0, 0, 0);
    }
  }
  float* red = S;   // reuse (S fully consumed before the P barrier)
#pragma unroll
  for (int ii = 0; ii < 2; ++ii)
#pragma unroll
    for (int jj = 0; jj < 4; ++jj)
#pragma unroll
      for (int r = 0; r < 4; ++r)
        red[w * 2048 + (ii * 16 + l4 * 4 + r) * 64 + jj * 16 + l15] = a2[ii][jj][r];
  __syncthreads();

  int c = tid & 63, r0 = tid >> 6;
#pragma unroll
  for (int q = 0; q < 8; ++q) {
    int row = r0 + q * 4;
    float s4 = red[row * 64 + c] + red[2048 + row * 64 + c] + red[4096 + row * 64 + c] + red[6144 + row * 64 + c];
    mhaB[(size_t)(b * Tt + tt * 32 + row) * 512 + h * 64 + c] = f2bf(s4);
  }
}

// ---------------- fused pointer logits + tanh clip + masked softmax ----------------
__global__ __launch_bounds__(256, 1)
void comp_k(const unsigned short* __restrict__ mhaO, const unsigned short* __restrict__ Ktb,
            const int* __restrict__ mask, float* __restrict__ out) {
  __shared__ __align__(16) float S[32 * 513];
  int bid = blockIdx.x;
  int x = bid & 7, i = bid >> 3;
  int b = x * 32 + (i >> 2);
  int tt = i & 3;
  int tid = threadIdx.x, lane = tid & 63, w = tid >> 6;
  int l15 = lane & 15, l4 = lane >> 4;

  f32x4 acc[2][8] = {};
#pragma unroll
  for (int ks = 0; ks < 16; ++ks) {
    bf16x8 fa[2];
#pragma unroll
    for (int ii = 0; ii < 2; ++ii)
      fa[ii] = *(const bf16x8*)(mhaO + (size_t)(b * Tt + tt * 32 + ii * 16 + l15) * 512 + ks * 32 + l4 * 8);
#pragma unroll
    for (int jj = 0; jj < 8; ++jj) {
      bf16x8 fbv = *(const bf16x8*)(Ktb + (size_t)(b * 512 + w * 128 + jj * 16 + l15) * 512 + ks * 32 + l4 * 8);
#pragma unroll
      for (int ii = 0; ii < 2; ++ii)
        acc[ii][jj] = __builtin_amdgcn_mfma_f32_16x16x32_bf16(fa[ii], fbv, acc[ii][jj], 0, 0, 0);
    }
  }
#pragma unroll
  for (int ii = 0; ii < 2; ++ii)
#pragma unroll
    for (int jj = 0; jj < 8; ++jj)
#pragma unroll
      for (int r = 0; r < 4; ++r)
        S[(ii * 16 + l4 * 4 + r) * 513 + w * 128 + jj * 16 + l15] = acc[ii][jj][r];
  __syncthreads();

  const float isd = 0.044194173824159216f;   // 1/sqrt(512)
#pragma unroll
  for (int rr = 0; rr < 8; ++rr) {
    int row = w * 8 + rr;
    int tg = tt * 32 + row;
    float v[8];
    float mx = -3.0e38f;
#pragma unroll
    for (int c8 = 0; c8 < 8; ++c8) {
      int c = lane + c8 * 64;
      float xv = tanhf(S[row * 513 + c] * isd) * 10.0f;
      int mv = mask[(size_t)tg * (Bb * Nn) + b * Nn + c];
      xv = mv ? NEGF : xv;
      v[c8] = xv;
      mx = fmaxf(mx, xv);
    }
#pragma unroll
    for (int off = 32; off >= 1; off >>= 1) mx = fmaxf(mx, __shfl_xor(mx, off));
    float sum = 0.f;
#pragma unroll
    for (int c8 = 0; c8 < 8; ++c8) { v[c8] = __expf(v[c8] - mx); sum += v[c8]; }
#pragma unroll
    for (int off = 32; off >= 1; off >>= 1) sum += __shfl_xor(sum, off);
    float inv = 1.0f / sum;
#pragma unroll
    for (int c8 = 0; c8 < 8; ++c8)
      out[(size_t)b * (Tt * Nn) + (size_t)tg * Nn + lane + c8 * 64] = v[c8] * inv;
  }
}

extern "C" void kernel_launch(void* const* d_in, const int* in_sizes, int n_in,
                              void* d_out, int out_size, void* d_ws, size_t ws_size,
                              hipStream_t stream) {
  (void)in_sizes; (void)n_in; (void)out_size; (void)ws_size;
  const float* emb  = (const float*)d_in[0];
  const float* mge  = (const float*)d_in[1];
  const float* cap  = (const float*)d_in[2];
  const float* Wk   = (const float*)d_in[3];
  const float* Wkt  = (const float*)d_in[4];
  const float* Wv   = (const float*)d_in[5];
  const float* Wqc  = (const float*)d_in[6];
  const float* Wqs  = (const float*)d_in[7];
  const float* Wout = (const float*)d_in[8];
  const int* prev   = (const int*)d_in[9];
  const int* mask   = (const int*)d_in[10];
  float* out = (float*)d_out;

  char* p = (char*)d_ws;
  auto take = [&](size_t n) { char* q = p; p += (n + 255) & ~(size_t)255; return q; };
  unsigned short* embB = (unsigned short*)take((size_t)131072 * 512 * 2);
  unsigned short* Kb   = (unsigned short*)take((size_t)131072 * 512 * 2);
  unsigned short* Vt   = (unsigned short*)take((size_t)131072 * 512 * 2);
  unsigned short* Ktb  = (unsigned short*)take((size_t)131072 * 512 * 2);
  unsigned short* SCe  = (unsigned short*)take((size_t)32768 * 512 * 2);
  float*          Qraw = (float*)take((size_t)32768 * 512 * 4);
  unsigned short* Qb   = (unsigned short*)take((size_t)32768 * 512 * 2);
  unsigned short* mhaB = (unsigned short*)take((size_t)32768 * 512 * 2);
  unsigned short* mhaO = (unsigned short*)take((size_t)32768 * 512 * 2);
  float*          Qc   = (float*)take((size_t)256 * 512 * 4);
  unsigned short* WkT  = (unsigned short*)take(524288);
  unsigned short* WktT = (unsigned short*)take(524288);
  unsigned short* WvT  = (unsigned short*)take(524288);
  unsigned short* WqsT = (unsigned short*)take(524288);
  unsigned short* WoutT= (unsigned short*)take(524288);

  cast_emb_k<<<32768, 256, 0, stream>>>(emb, embB, 8388608);
  cast_wt_k<<<1280, 256, 0, stream>>>(Wk, Wkt, Wv, Wqs, Wout, WkT, WktT, WvT, WqsT, WoutT);
  qc_k<<<256, 256, 0, stream>>>(mge, Wqc, Qc);
  gather_k<<<8192, 256, 0, stream>>>(embB, prev, SCe);
  gemm_bt_k<0><<<1024, 256, 0, stream>>>(SCe, WqsT, Qraw, 256);
  qfix_k<<<32768, 256, 0, stream>>>(Qraw, Qc, Wqs, cap, Qb);
  gemm_bt_k<1><<<4096, 256, 0, stream>>>(embB, WkT, Kb, 1024);
  gemm_bt_k<2><<<4096, 256, 0, stream>>>(embB, WvT, Vt, 1024);
  gemm_bt_k<1><<<4096, 256, 0, stream>>>(embB, WktT, Ktb, 1024);
  attn_k<<<8192, 256, 0, stream>>>(Qb, Kb, Vt, mask, mhaB);
  gemm_bt_k<1><<<1024, 256, 0, stream>>>(mhaB, WoutT, mhaO, 256);
  comp_k<<<1024, 256, 0, stream>>>(mhaO, Ktb, mask, out);
}

// Round 2
// 994.025 us; speedup vs baseline: 1.0529x; 1.0529x over previous
//
#include <hip/hip_runtime.h>
#include <hip/hip_bf16.h>

// Problem constants
constexpr int Bb = 256;   // batch
constexpr int Nn = 512;   // nodes
constexpr int Dd = 512;   // model dim
constexpr int Hh = 8;     // heads
constexpr int Tt = 128;   // steps
#define NEGF (-1.0e9f)

typedef __attribute__((ext_vector_type(4))) float f32x4;
typedef __attribute__((ext_vector_type(8))) short bf16x8;     // MFMA a/b frag (8 bf16)
typedef __attribute__((ext_vector_type(8))) unsigned short u16x8;

__device__ __forceinline__ unsigned short f2bf(float f) {
  union { float f; unsigned u; } v; v.f = f;
  unsigned r = v.u + 0x7fffu + ((v.u >> 16) & 1u);   // RNE
  return (unsigned short)(r >> 16);
}

// ---------------- cast embeddings f32 -> bf16 ----------------
__global__ void cast_emb_k(const float* __restrict__ src, unsigned short* __restrict__ dst, int n8) {
  int i = blockIdx.x * 256 + threadIdx.x;
  if (i >= n8) return;
  const float4* s = (const float4*)src + (size_t)i * 2;
  float4 a = s[0], b = s[1];
  u16x8 o;
  o[0] = f2bf(a.x); o[1] = f2bf(a.y); o[2] = f2bf(a.z); o[3] = f2bf(a.w);
  o[4] = f2bf(b.x); o[5] = f2bf(b.y); o[6] = f2bf(b.z); o[7] = f2bf(b.w);
  ((u16x8*)dst)[i] = o;
}

// ---------------- transpose-cast 512x512 weight blocks to [n][k] bf16 ----------------
__global__ void cast_wt_k(const float* __restrict__ W0, const float* __restrict__ W1,
                          const float* __restrict__ W2, const float* __restrict__ W3,
                          const float* __restrict__ W4,
                          unsigned short* __restrict__ D0, unsigned short* __restrict__ D1,
                          unsigned short* __restrict__ D2, unsigned short* __restrict__ D3,
                          unsigned short* __restrict__ D4) {
  int mid = blockIdx.x >> 8;
  int tile = blockIdx.x & 255;
  const float* S = (mid == 0) ? W0 : (mid == 1) ? W1 : (mid == 2) ? W2 : (mid == 3) ? W3 : W4;
  unsigned short* Dst = (mid == 0) ? D0 : (mid == 1) ? D1 : (mid == 2) ? D2 : (mid == 3) ? D3 : D4;
  __shared__ float t[32][33];
  int r0 = (tile >> 4) * 32, c0 = (tile & 15) * 32;
  int tx = threadIdx.x & 31, ty = threadIdx.x >> 5;
#pragma unroll
  for (int yy = 0; yy < 4; ++yy) {
    int r = ty + yy * 8;
    t[r][tx] = S[(size_t)(r0 + r) * 512 + c0 + tx];
  }
  __syncthreads();
#pragma unroll
  for (int yy = 0; yy < 4; ++yy) {
    int c = ty + yy * 8;
    Dst[(size_t)(c0 + c) * 512 + r0 + tx] = f2bf(t[tx][c]);   // Dst[n][k] = W[k][n]
  }
}

// ---------------- Q_context = mge @ Wqc (f32) ----------------
__global__ void qc_k(const float* __restrict__ mge, const float* __restrict__ Wqc,
                     float* __restrict__ Qc) {
  int b = blockIdx.x;
  __shared__ float m[512];
  m[threadIdx.x] = mge[(size_t)b * 512 + threadIdx.x];
  m[threadIdx.x + 256] = mge[(size_t)b * 512 + threadIdx.x + 256];
  __syncthreads();
  float a0 = 0.f, a1 = 0.f;
  for (int k = 0; k < 512; ++k) {
    float mk = m[k];
    a0 += mk * Wqc[(size_t)k * 512 + threadIdx.x];
    a1 += mk * Wqc[(size_t)k * 512 + threadIdx.x + 256];
  }
  Qc[(size_t)b * 512 + threadIdx.x] = a0;
  Qc[(size_t)b * 512 + threadIdx.x + 256] = a1;
}

// ---------------- gather step-context rows (bf16) ----------------
__global__ void gather_k(const unsigned short* __restrict__ embB, const int* __restrict__ prev,
                         unsigned short* __restrict__ SC) {
  int row = blockIdx.x * 4 + (threadIdx.x >> 6);   // row = t*B + b
  int lane = threadIdx.x & 63;
  int t = row >> 8, b = row & 255;
  int pa = prev[t * Bb + b];
  const u16x8* s = (const u16x8*)(embB + (size_t)(b * 512 + pa) * 512) + lane;
  *((u16x8*)(SC + (size_t)row * 512) + lane) = *s;
}

// ---------------- mask -> bitmask  bits[b][t][16 words] ----------------
__global__ void mbits_k(const int* __restrict__ mask, unsigned* __restrict__ bits) {
  size_t gid = (size_t)blockIdx.x * 256 + threadIdx.x;   // element over T*B*N
  int mv = mask[gid];
  unsigned long long bal = __ballot(mv == 1);
  if ((threadIdx.x & 63) == 0) {
    unsigned t = (unsigned)(gid >> 17);
    unsigned b = (unsigned)((gid >> 9) & 255);
    unsigned n = (unsigned)(gid & 511);
    unsigned* dst = bits + (((size_t)b * 128 + t) * 16 + (n >> 5));
    dst[0] = (unsigned)bal;
    dst[1] = (unsigned)(bal >> 32);
  }
}

// ---------------- GEMM C[M,512] = A[M,512] x BT[512,512]^T  (bf16 MFMA) ----------------
// MODE 1: bf16 out; MODE 2: bf16 transposed out (Vt[b][d][n]);
// MODE 3: q-epilogue -> Qb[(b*T+t)][d] = bf16((acc + Qc[b] + (1-cap)*WqsL) / 8)
template <int MODE>
__global__ __launch_bounds__(256, 2)
void gemm_bt_k(const unsigned short* __restrict__ A, const unsigned short* __restrict__ BT,
               void* __restrict__ Cout, int MT,
               const float* __restrict__ Qc, const float* __restrict__ WqsL,
               const float* __restrict__ capp) {
  __shared__ __align__(16) char lds[32768];   // A tile [128][64], B tile [128][64], swizzled
  int bid = blockIdx.x;
  int x = bid & 7;
  int i = bid >> 3;
  int per = MT >> 3;
  int nt = i & 3;
  int mt = x * per + (i >> 2);
  int m0 = mt * 128, n0 = nt * 128;
  int tid = threadIdx.x;
  int lane = tid & 63;
  int wid = tid >> 6;
  int wm = wid >> 1, wn = wid & 1;
  int l15 = lane & 15, l4 = lane >> 4;

  f32x4 acc[4][4] = {};

  for (int k0 = 0; k0 < 512; k0 += 64) {
    __syncthreads();
#pragma unroll
    for (int c4 = 0; c4 < 4; ++c4) {
      int ch = tid + c4 * 256;
      int r = ch >> 3, cb = ch & 7;
      u16x8 v = *(const u16x8*)(A + (size_t)(m0 + r) * 512 + k0 + cb * 8);
      *(u16x8*)(lds + r * 128 + ((cb * 16) ^ ((r & 7) << 4))) = v;
    }
#pragma unroll
    for (int c4 = 0; c4 < 4; ++c4) {
      int ch = tid + c4 * 256;
      int r = ch >> 3, cb = ch & 7;
      u16x8 v = *(const u16x8*)(BT + (size_t)(n0 + r) * 512 + k0 + cb * 8);
      *(u16x8*)(lds + 16384 + r * 128 + ((cb * 16) ^ ((r & 7) << 4))) = v;
    }
    __syncthreads();
#pragma unroll
    for (int ks = 0; ks < 2; ++ks) {
      bf16x8 fa[4], fb[4];
#pragma unroll
      for (int ii = 0; ii < 4; ++ii) {
        int r = wm * 64 + ii * 16 + l15;
        int kb = ks * 64 + l4 * 16;
        fa[ii] = *(const bf16x8*)(lds + r * 128 + (kb ^ ((r & 7) << 4)));
      }
#pragma unroll
      for (int jj = 0; jj < 4; ++jj) {
        int r = wn * 64 + jj * 16 + l15;
        int kb = ks * 64 + l4 * 16;
        fb[jj] = *(const bf16x8*)(lds + 16384 + r * 128 + (kb ^ ((r & 7) << 4)));
      }
#pragma unroll
      for (int ii = 0; ii < 4; ++ii)
#pragma unroll
        for (int jj = 0; jj < 4; ++jj)
          acc[ii][jj] = __builtin_amdgcn_mfma_f32_16x16x32_bf16(fa[ii], fb[jj], acc[ii][jj], 0, 0, 0);
    }
  }

  if (MODE == 1) {
    unsigned short* C = (unsigned short*)Cout;
#pragma unroll
    for (int ii = 0; ii < 4; ++ii)
#pragma unroll
      for (int jj = 0; jj < 4; ++jj)
#pragma unroll
        for (int r = 0; r < 4; ++r) {
          int row = m0 + wm * 64 + ii * 16 + l4 * 4 + r;
          int col = n0 + wn * 64 + jj * 16 + l15;
          C[(size_t)row * 512 + col] = f2bf(acc[ii][jj][r]);
        }
  } else if (MODE == 2) {
    // transposed write: Vt[b][d][n]
    int bb = m0 >> 9, nn0 = m0 & 511, d0 = n0;
    unsigned short* C = (unsigned short*)Cout;
#pragma unroll
    for (int p = 0; p < 2; ++p) {
      __syncthreads();
      if (wn == p) {
#pragma unroll
        for (int ii = 0; ii < 4; ++ii)
#pragma unroll
          for (int jj = 0; jj < 4; ++jj)
#pragma unroll
            for (int r = 0; r < 4; ++r) {
              int d = jj * 16 + l15;
              int m = wm * 64 + ii * 16 + l4 * 4 + r;
              *(unsigned short*)(lds + d * 272 + m * 2) = f2bf(acc[ii][jj][r]);
            }
      }
      __syncthreads();
      int dl = tid >> 2, seg = tid & 3;
      const char* sp = lds + dl * 272 + seg * 64;
      unsigned short* dp = C + (size_t)(bb * 512 + d0 + p * 64 + dl) * 512 + nn0 + seg * 32;
      *(u16x8*)(dp) = *(const u16x8*)(sp);
      *(u16x8*)(dp + 8) = *(const u16x8*)(sp + 16);
      *(u16x8*)(dp + 16) = *(const u16x8*)(sp + 32);
      *(u16x8*)(dp + 24) = *(const u16x8*)(sp + 48);
    }
  } else {
    // MODE 3: rows m = t*256 + b; write Qb[(b*128+t)*512 + col] = bf16((acc + Qc + (1-cap)*WqsL)/8)
    unsigned short* C = (unsigned short*)Cout;
#pragma unroll
    for (int ii = 0; ii < 4; ++ii)
#pragma unroll
      for (int jj = 0; jj < 4; ++jj)
#pragma unroll
        for (int r = 0; r < 4; ++r) {
          int row = m0 + wm * 64 + ii * 16 + l4 * 4 + r;
          int col = n0 + wn * 64 + jj * 16 + l15;
          int t = row >> 8, bbx = row & 255;
          float val = acc[ii][jj][r] + Qc[(size_t)bbx * 512 + col] + (1.0f - capp[row]) * WqsL[col];
          C[(size_t)(bbx * 128 + t) * 512 + col] = f2bf(val * 0.125f);
        }
  }
}

// ---------------- flash-style MHA: one block per (b,h), 4 independent waves ----------------
__global__ __launch_bounds__(256, 2)
void attn2_k(const unsigned short* __restrict__ Qb, const unsigned short* __restrict__ Kb,
             const unsigned short* __restrict__ Vt, const unsigned* __restrict__ mbits,
             unsigned short* __restrict__ mhaB) {
  __shared__ __align__(16) char Pb[4][4096];   // per-wave P patch: 32 rows x 128B, XOR-swizzled
  int bid = blockIdx.x;
  int h = bid & 7, b = bid >> 3;
  int tid = threadIdx.x, lane = tid & 63, w = tid >> 6;
  int l15 = lane & 15, l4 = lane >> 4;
  int tbase = w * 32;
  char* myP = Pb[w];

  // Q fragments (1/sqrt(hd) folded into Qb)
  bf16x8 aq[2][2];
#pragma unroll
  for (int ii = 0; ii < 2; ++ii)
#pragma unroll
    for (int kk = 0; kk < 2; ++kk)
      aq[ii][kk] = *(const bf16x8*)(Qb + (size_t)(b * Tt + tbase + ii * 16 + l15) * 512 + h * 64 + kk * 32 + l4 * 8);

  f32x4 o[2][4] = {};
  float m_run[2][4], s_run[2][4];
#pragma unroll
  for (int ii = 0; ii < 2; ++ii)
#pragma unroll
    for (int r = 0; r < 4; ++r) { m_run[ii][r] = -3.0e38f; s_run[ii][r] = 0.f; }

  for (int c = 0; c < 8; ++c) {          // n-chunks of 64
    // S chunk = Q K^T
    f32x4 acc[2][4] = {};
#pragma unroll
    for (int jj = 0; jj < 4; ++jj) {
      const unsigned short* kp = Kb + (size_t)(b * 512 + c * 64 + jj * 16 + l15) * 512 + h * 64 + l4 * 8;
      bf16x8 k0 = *(const bf16x8*)(kp);
      bf16x8 k1 = *(const bf16x8*)(kp + 32);
#pragma unroll
      for (int ii = 0; ii < 2; ++ii) {
        acc[ii][jj] = __builtin_amdgcn_mfma_f32_16x16x32_bf16(aq[ii][0], k0, acc[ii][jj], 0, 0, 0);
        acc[ii][jj] = __builtin_amdgcn_mfma_f32_16x16x32_bf16(aq[ii][1], k1, acc[ii][jj], 0, 0, 0);
      }
    }
    // online masked softmax per row; P -> LDS (bf16, swizzled)
#pragma unroll
    for (int ii = 0; ii < 2; ++ii)
#pragma unroll
      for (int r = 0; r < 4; ++r) {
        int rowl = ii * 16 + l4 * 4 + r;
        int t = tbase + rowl;
        const unsigned* mw = mbits + (((size_t)b * Tt + t) << 4) + c * 2;
        unsigned w0 = mw[0], w1 = mw[1];
        float x0 = ((w0 >> l15) & 1) ? NEGF : acc[ii][0][r];
        float x1 = ((w0 >> (16 + l15)) & 1) ? NEGF : acc[ii][1][r];
        float x2 = ((w1 >> l15) & 1) ? NEGF : acc[ii][2][r];
        float x3 = ((w1 >> (16 + l15)) & 1) ? NEGF : acc[ii][3][r];
        float cm = fmaxf(fmaxf(x0, x1), fmaxf(x2, x3));
        cm = fmaxf(cm, __shfl_xor(cm, 1));
        cm = fmaxf(cm, __shfl_xor(cm, 2));
        cm = fmaxf(cm, __shfl_xor(cm, 4));
        cm = fmaxf(cm, __shfl_xor(cm, 8));
        float mo = m_run[ii][r];
        float mn = fmaxf(mo, cm);
        float al = __expf(mo - mn);
        m_run[ii][r] = mn;
        float p0 = __expf(x0 - mn), p1 = __expf(x1 - mn);
        float p2 = __expf(x2 - mn), p3 = __expf(x3 - mn);
        s_run[ii][r] = s_run[ii][r] * al + (p0 + p1 + p2 + p3);
#pragma unroll
        for (int jd = 0; jd < 4; ++jd) o[ii][jd][r] *= al;
        int swz = (rowl & 7) << 4;
        char* pp = myP + rowl * 128;
        *(unsigned short*)(pp + ((l15 * 2) ^ swz)) = f2bf(p0);
        *(unsigned short*)(pp + ((32 + l15 * 2) ^ swz)) = f2bf(p1);
        *(unsigned short*)(pp + ((64 + l15 * 2) ^ swz)) = f2bf(p2);
        *(unsigned short*)(pp + ((96 + l15 * 2) ^ swz)) = f2bf(p3);
      }
    // PV
#pragma unroll
    for (int ks = 0; ks < 2; ++ks) {
      bf16x8 pa[2];
#pragma unroll
      for (int ii = 0; ii < 2; ++ii) {
        int rowl = ii * 16 + l15;
        pa[ii] = *(const bf16x8*)(myP + rowl * 128 + ((ks * 64 + l4 * 16) ^ ((rowl & 7) << 4)));
      }
#pragma unroll
      for (int jd = 0; jd < 4; ++jd) {
        bf16x8 vb = *(const bf16x8*)(Vt + (size_t)(b * 512 + h * 64 + jd * 16 + l15) * 512 + c * 64 + ks * 32 + l4 * 8);
#pragma unroll
        for (int ii = 0; ii < 2; ++ii)
          o[ii][jd] = __builtin_amdgcn_mfma_f32_16x16x32_bf16(pa[ii], vb, o[ii][jd], 0, 0, 0);
      }
    }
  }

  float inv[2][4];
#pragma unroll
  for (int ii = 0; ii < 2; ++ii)
#pragma unroll
    for (int r = 0; r < 4; ++r) {
      float s = s_run[ii][r];
      s += __shfl_xor(s, 1); s += __shfl_xor(s, 2);
      s += __shfl_xor(s, 4); s += __shfl_xor(s, 8);
      inv[ii][r] = 1.0f / s;
    }
#pragma unroll
  for (int ii = 0; ii < 2; ++ii)
#pragma unroll
    for (int jd = 0; jd < 4; ++jd)
#pragma unroll
      for (int r = 0; r < 4; ++r) {
        int t = tbase + ii * 16 + l4 * 4 + r;
        mhaB[(size_t)(b * Tt + t) * 512 + h * 64 + jd * 16 + l15] = f2bf(o[ii][jd][r] * inv[ii][r]);
      }
}

// ---------------- pointer logits + tanh clip + masked softmax (no max pass needed) ----------------
__global__ __launch_bounds__(512, 2)
void comp2_k(const unsigned short* __restrict__ mhaO, const unsigned short* __restrict__ Ktb,
             const unsigned* __restrict__ mbits, float* __restrict__ out) {
  int b = blockIdx.x;
  int tid = threadIdx.x, lane = tid & 63, w = tid >> 6;
  int l15 = lane & 15, l4 = lane >> 4;
  int tbase = w * 16;

  f32x4 acc[32] = {};
#pragma unroll
  for (int ks = 0; ks < 16; ++ks) {
    bf16x8 fa = *(const bf16x8*)(mhaO + (size_t)(b * Tt + tbase + l15) * 512 + ks * 32 + l4 * 8);
#pragma unroll
    for (int jj = 0; jj < 32; ++jj) {
      bf16x8 kb = *(const bf16x8*)(Ktb + (size_t)(b * 512 + jj * 16 + l15) * 512 + ks * 32 + l4 * 8);
      acc[jj] = __builtin_amdgcn_mfma_f32_16x16x32_bf16(fa, kb, acc[jj], 0, 0, 0);
    }
  }

  const float isd = 0.044194173824159216f;   // 1/sqrt(512)
#pragma unroll
  for (int r = 0; r < 4; ++r) {
    int t = tbase + l4 * 4 + r;
    uint4 mv[4];
#pragma unroll
    for (int q = 0; q < 4; ++q)
      mv[q] = *(const uint4*)(mbits + (((size_t)b * Tt + t) << 4) + q * 4);
    const unsigned* mw = (const unsigned*)mv;
    float pv[32];
    float s = 0.f;
#pragma unroll
    for (int jj = 0; jj < 32; ++jj) {
      unsigned word = mw[jj >> 1];
      int bit = (word >> (((jj & 1) << 4) + l15)) & 1;
      float y = acc[jj][r] * isd;
      y = fminf(fmaxf(y, -15.f), 15.f);
      float e2 = __expf(2.f * y);
      float th = (e2 - 1.f) / (e2 + 1.f);
      float xv = bit ? NEGF : th * 10.f;
      float p = __expf(xv - 10.f);     // max of tanh*10 is 10 -> exact softmax, no max pass
      pv[jj] = p; s += p;
    }
    s += __shfl_xor(s, 1); s += __shfl_xor(s, 2);
    s += __shfl_xor(s, 4); s += __shfl_xor(s, 8);
    float inv = 1.0f / s;
#pragma unroll
    for (int jj = 0; jj < 32; ++jj)
      out[((size_t)b * Tt + t) * 512 + jj * 16 + l15] = pv[jj] * inv;
  }
}

extern "C" void kernel_launch(void* const* d_in, const int* in_sizes, int n_in,
                              void* d_out, int out_size, void* d_ws, size_t ws_size,
                              hipStream_t stream) {
  (void)in_sizes; (void)n_in; (void)out_size; (void)ws_size;
  const float* emb  = (const float*)d_in[0];
  const float* mge  = (const float*)d_in[1];
  const float* cap  = (const float*)d_in[2];
  const float* Wk   = (const float*)d_in[3];
  const float* Wkt  = (const float*)d_in[4];
  const float* Wv   = (const float*)d_in[5];
  const float* Wqc  = (const float*)d_in[6];
  const float* Wqs  = (const float*)d_in[7];
  const float* Wout = (const float*)d_in[8];
  const int* prev   = (const int*)d_in[9];
  const int* mask   = (const int*)d_in[10];
  float* out = (float*)d_out;

  char* p = (char*)d_ws;
  auto take = [&](size_t n) { char* q = p; p += (n + 255) & ~(size_t)255; return q; };
  unsigned short* embB = (unsigned short*)take((size_t)131072 * 512 * 2);
  unsigned short* Kb   = (unsigned short*)take((size_t)131072 * 512 * 2);
  unsigned short* Vt   = (unsigned short*)take((size_t)131072 * 512 * 2);
  unsigned short* Ktb  = (unsigned short*)take((size_t)131072 * 512 * 2);
  unsigned short* SCe  = (unsigned short*)take((size_t)32768 * 512 * 2);
  unsigned short* Qb   = (unsigned short*)take((size_t)32768 * 512 * 2);
  unsigned short* mhaB = (unsigned short*)take((size_t)32768 * 512 * 2);
  unsigned short* mhaO = (unsigned short*)take((size_t)32768 * 512 * 2);
  float*          Qc   = (float*)take((size_t)256 * 512 * 4);
  unsigned*       mbit = (unsigned*)take((size_t)256 * 128 * 16 * 4);
  unsigned short* WkT  = (unsigned short*)take(524288);
  unsigned short* WktT = (unsigned short*)take(524288);
  unsigned short* WvT  = (unsigned short*)take(524288);
  unsigned short* WqsT = (unsigned short*)take(524288);
  unsigned short* WoutT= (unsigned short*)take(524288);

  cast_emb_k<<<32768, 256, 0, stream>>>(emb, embB, 8388608);
  cast_wt_k<<<1280, 256, 0, stream>>>(Wk, Wkt, Wv, Wqs, Wout, WkT, WktT, WvT, WqsT, WoutT);
  qc_k<<<256, 256, 0, stream>>>(mge, Wqc, Qc);
  gather_k<<<8192, 256, 0, stream>>>(embB, prev, SCe);
  mbits_k<<<65536, 256, 0, stream>>>(mask, mbit);
  gemm_bt_k<3><<<1024, 256, 0, stream>>>(SCe, WqsT, Qb, 256, Qc, Wqs + 512 * 512, cap);
  gemm_bt_k<1><<<4096, 256, 0, stream>>>(embB, WkT, Kb, 1024, nullptr, nullptr, nullptr);
  gemm_bt_k<2><<<4096, 256, 0, stream>>>(embB, WvT, Vt, 1024, nullptr, nullptr, nullptr);
  gemm_bt_k<1><<<4096, 256, 0, stream>>>(embB, WktT, Ktb, 1024, nullptr, nullptr, nullptr);
  attn2_k<<<2048, 256, 0, stream>>>(Qb, Kb, Vt, mbit, mhaB);
  gemm_bt_k<1><<<1024, 256, 0, stream>>>(mhaB, WoutT, mhaO, 256, nullptr, nullptr, nullptr);
  comp2_k<<<256, 512, 0, stream>>>(mhaO, Ktb, mbit, out);
}

// Round 3
// 987.693 us; speedup vs baseline: 1.0596x; 1.0064x over previous
//
#include <hip/hip_runtime.h>
#include <hip/hip_bf16.h>

// Problem constants
constexpr int Bb = 256;   // batch
constexpr int Nn = 512;   // nodes
constexpr int Dd = 512;   // model dim
constexpr int Hh = 8;     // heads
constexpr int Tt = 128;   // steps
#define NEGF (-1.0e9f)

typedef __attribute__((ext_vector_type(4))) float f32x4;
typedef __attribute__((ext_vector_type(8))) short bf16x8;     // MFMA a/b frag (8 bf16)
typedef __attribute__((ext_vector_type(8))) unsigned short u16x8;

__device__ __forceinline__ unsigned short f2bf(float f) {
  union { float f; unsigned u; } v; v.f = f;
  unsigned r = v.u + 0x7fffu + ((v.u >> 16) & 1u);   // RNE
  return (unsigned short)(r >> 16);
}

__device__ __forceinline__ unsigned cvtpk(float lo, float hi) {
  unsigned r;
  asm("v_cvt_pk_bf16_f32 %0, %1, %2" : "=v"(r) : "v"(lo), "v"(hi));
  return r;
}

// ---------------- cast embeddings f32 -> bf16 ----------------
__global__ void cast_emb_k(const float* __restrict__ src, unsigned short* __restrict__ dst, int n8) {
  int i = blockIdx.x * 256 + threadIdx.x;
  if (i >= n8) return;
  const float4* s = (const float4*)src + (size_t)i * 2;
  float4 a = s[0], b = s[1];
  u16x8 o;
  o[0] = f2bf(a.x); o[1] = f2bf(a.y); o[2] = f2bf(a.z); o[3] = f2bf(a.w);
  o[4] = f2bf(b.x); o[5] = f2bf(b.y); o[6] = f2bf(b.z); o[7] = f2bf(b.w);
  ((u16x8*)dst)[i] = o;
}

// ---------------- transpose-cast 512x512 weight blocks to [n][k] bf16 ----------------
__global__ void cast_wt_k(const float* __restrict__ W0, const float* __restrict__ W1,
                          const float* __restrict__ W2, const float* __restrict__ W3,
                          const float* __restrict__ W4,
                          unsigned short* __restrict__ D0, unsigned short* __restrict__ D1,
                          unsigned short* __restrict__ D2, unsigned short* __restrict__ D3,
                          unsigned short* __restrict__ D4) {
  int mid = blockIdx.x >> 8;
  int tile = blockIdx.x & 255;
  const float* S = (mid == 0) ? W0 : (mid == 1) ? W1 : (mid == 2) ? W2 : (mid == 3) ? W3 : W4;
  unsigned short* Dst = (mid == 0) ? D0 : (mid == 1) ? D1 : (mid == 2) ? D2 : (mid == 3) ? D3 : D4;
  __shared__ float t[32][33];
  int r0 = (tile >> 4) * 32, c0 = (tile & 15) * 32;
  int tx = threadIdx.x & 31, ty = threadIdx.x >> 5;
#pragma unroll
  for (int yy = 0; yy < 4; ++yy) {
    int r = ty + yy * 8;
    t[r][tx] = S[(size_t)(r0 + r) * 512 + c0 + tx];
  }
  __syncthreads();
#pragma unroll
  for (int yy = 0; yy < 4; ++yy) {
    int c = ty + yy * 8;
    Dst[(size_t)(c0 + c) * 512 + r0 + tx] = f2bf(t[tx][c]);   // Dst[n][k] = W[k][n]
  }
}

// ---------------- Q_context = mge @ Wqc (f32) ----------------
__global__ void qc_k(const float* __restrict__ mge, const float* __restrict__ Wqc,
                     float* __restrict__ Qc) {
  int b = blockIdx.x;
  __shared__ float m[512];
  m[threadIdx.x] = mge[(size_t)b * 512 + threadIdx.x];
  m[threadIdx.x + 256] = mge[(size_t)b * 512 + threadIdx.x + 256];
  __syncthreads();
  float a0 = 0.f, a1 = 0.f;
  for (int k = 0; k < 512; ++k) {
    float mk = m[k];
    a0 += mk * Wqc[(size_t)k * 512 + threadIdx.x];
    a1 += mk * Wqc[(size_t)k * 512 + threadIdx.x + 256];
  }
  Qc[(size_t)b * 512 + threadIdx.x] = a0;
  Qc[(size_t)b * 512 + threadIdx.x + 256] = a1;
}

// ---------------- gather step-context rows (bf16) ----------------
__global__ void gather_k(const unsigned short* __restrict__ embB, const int* __restrict__ prev,
                         unsigned short* __restrict__ SC) {
  int row = blockIdx.x * 4 + (threadIdx.x >> 6);   // row = t*B + b
  int lane = threadIdx.x & 63;
  int t = row >> 8, b = row & 255;
  int pa = prev[t * Bb + b];
  const u16x8* s = (const u16x8*)(embB + (size_t)(b * 512 + pa) * 512) + lane;
  *((u16x8*)(SC + (size_t)row * 512) + lane) = *s;
}

// ---------------- mask -> bitmask  bits[b][t][16 words] ----------------
__global__ void mbits_k(const int* __restrict__ mask, unsigned* __restrict__ bits) {
  size_t gid = (size_t)blockIdx.x * 256 + threadIdx.x;   // element over T*B*N
  int mv = mask[gid];
  unsigned long long bal = __ballot(mv == 1);
  if ((threadIdx.x & 63) == 0) {
    unsigned t = (unsigned)(gid >> 17);
    unsigned b = (unsigned)((gid >> 9) & 255);
    unsigned n = (unsigned)(gid & 511);
    unsigned* dst = bits + (((size_t)b * 128 + t) * 16 + (n >> 5));
    dst[0] = (unsigned)bal;
    dst[1] = (unsigned)(bal >> 32);
  }
}

// ---------------- shared staging: 128x64 bf16 tile via global_load_lds (16B) ----------------
__device__ __forceinline__ void stage_tile(const unsigned short* __restrict__ G, int row0, int k0,
                                           unsigned short* lds_base, int wave, int lane) {
#pragma unroll
  for (int c = 0; c < 4; ++c) {
    int chunk = wave * 4 + c;                       // 16 chunks of 1KB (8 rows each)
    const unsigned short* g = G + (size_t)(row0 + chunk * 8 + (lane >> 3)) * 512 + k0 + (lane & 7) * 8;
    __builtin_amdgcn_global_load_lds((__attribute__((address_space(1))) void*)g,
                                     (__attribute__((address_space(3))) void*)(lds_base + chunk * 512),
                                     16, 0, 0);
  }
}

// ---------------- GEMM (m97 structure): C[M,512] = A[M,512] x BT[512,512]^T ----------------
// MODE 1: bf16 out; MODE 3: q-epilogue.  M = 32768 fixed (32 m-tiles/XCD).
template <int MODE>
__global__ __launch_bounds__(256, 2)
void gemm5_k(const unsigned short* __restrict__ A, const unsigned short* __restrict__ BT,
             void* __restrict__ Cout,
             const float* __restrict__ Qc, const float* __restrict__ WqsL,
             const float* __restrict__ capp) {
  __shared__ __align__(16) char lds[32768];
  unsigned short* ldsA = (unsigned short*)lds;
  unsigned short* ldsB = ldsA + 8192;
  int xcd = blockIdx.x & 7, loc = blockIdx.x >> 3;
  int ml = loc >> 2, nt = loc & 3;
  int mt = xcd * 32 + ml;
  int m0 = mt * 128, n0 = nt * 128;
  int tid = threadIdx.x, lane = tid & 63, w = tid >> 6;
  int wm = w >> 1, wn = w & 1;
  int l15 = lane & 15, l4 = lane >> 4;

  f32x4 acc[4][4] = {};
  for (int k0 = 0; k0 < 512; k0 += 64) {
    stage_tile(A, m0, k0, ldsA, w, lane);
    stage_tile(BT, n0, k0, ldsB, w, lane);
    __syncthreads();
#pragma unroll
    for (int ks = 0; ks < 2; ++ks) {
      bf16x8 fa[4], fb[4];
#pragma unroll
      for (int ii = 0; ii < 4; ++ii)
        fa[ii] = *(const bf16x8*)(ldsA + (wm * 64 + ii * 16 + l15) * 64 + ks * 32 + l4 * 8);
#pragma unroll
      for (int jj = 0; jj < 4; ++jj)
        fb[jj] = *(const bf16x8*)(ldsB + (wn * 64 + jj * 16 + l15) * 64 + ks * 32 + l4 * 8);
#pragma unroll
      for (int ii = 0; ii < 4; ++ii)
#pragma unroll
        for (int jj = 0; jj < 4; ++jj)
          acc[ii][jj] = __builtin_amdgcn_mfma_f32_16x16x32_bf16(fa[ii], fb[jj], acc[ii][jj], 0, 0, 0);
    }
    __syncthreads();
  }

  if (MODE == 1) {
    unsigned short* C = (unsigned short*)Cout;
#pragma unroll
    for (int ii = 0; ii < 4; ++ii)
#pragma unroll
      for (int jj = 0; jj < 4; ++jj)
#pragma unroll
        for (int r = 0; r < 4; ++r) {
          int row = m0 + wm * 64 + ii * 16 + l4 * 4 + r;
          int col = n0 + wn * 64 + jj * 16 + l15;
          C[(size_t)row * 512 + col] = f2bf(acc[ii][jj][r]);
        }
  } else {
    // MODE 3: rows m = t*256 + b; write Qb[(b*128+t)*512+col] = bf16((acc+Qc+(1-cap)*WqsL)/8)
    unsigned short* C = (unsigned short*)Cout;
#pragma unroll
    for (int ii = 0; ii < 4; ++ii)
#pragma unroll
      for (int jj = 0; jj < 4; ++jj)
#pragma unroll
        for (int r = 0; r < 4; ++r) {
          int row = m0 + wm * 64 + ii * 16 + l4 * 4 + r;
          int col = n0 + wn * 64 + jj * 16 + l15;
          int t = row >> 8, bbx = row & 255;
          float val = acc[ii][jj][r] + Qc[(size_t)bbx * 512 + col] + (1.0f - capp[row]) * WqsL[col];
          C[(size_t)(bbx * 128 + t) * 512 + col] = f2bf(val * 0.125f);
        }
  }
}

// ---------------- fused triple GEMM: embB x {WkT,WktT,WvT} -> {Kb, Ktb, Vt(transposed)} ----------------
__global__ __launch_bounds__(256, 2)
void gemm5f_k(const unsigned short* __restrict__ A,
              const unsigned short* __restrict__ B0, const unsigned short* __restrict__ B1,
              const unsigned short* __restrict__ B2,
              unsigned short* __restrict__ C0, unsigned short* __restrict__ C1,
              unsigned short* __restrict__ C2) {
  __shared__ __align__(16) char lds[32768];
  unsigned short* ldsA = (unsigned short*)lds;
  unsigned short* ldsB = ldsA + 8192;
  int xcd = blockIdx.x & 7, loc = blockIdx.x >> 3;   // loc < 1536
  int ml = loc / 12, nt = loc - ml * 12;             // n fastest: A-tile L2 reuse x12
  int mt = xcd * 128 + ml;
  int m0 = mt * 128;
  int grp = nt >> 2, nn = nt & 3;
  const unsigned short* BT = (grp == 0) ? B0 : (grp == 1) ? B1 : B2;
  int n0 = nn * 128;
  int tid = threadIdx.x, lane = tid & 63, w = tid >> 6;
  int wm = w >> 1, wn = w & 1;
  int l15 = lane & 15, l4 = lane >> 4;

  f32x4 acc[4][4] = {};
  for (int k0 = 0; k0 < 512; k0 += 64) {
    stage_tile(A, m0, k0, ldsA, w, lane);
    stage_tile(BT, n0, k0, ldsB, w, lane);
    __syncthreads();
#pragma unroll
    for (int ks = 0; ks < 2; ++ks) {
      bf16x8 fa[4], fb[4];
#pragma unroll
      for (int ii = 0; ii < 4; ++ii)
        fa[ii] = *(const bf16x8*)(ldsA + (wm * 64 + ii * 16 + l15) * 64 + ks * 32 + l4 * 8);
#pragma unroll
      for (int jj = 0; jj < 4; ++jj)
        fb[jj] = *(const bf16x8*)(ldsB + (wn * 64 + jj * 16 + l15) * 64 + ks * 32 + l4 * 8);
#pragma unroll
      for (int ii = 0; ii < 4; ++ii)
#pragma unroll
        for (int jj = 0; jj < 4; ++jj)
          acc[ii][jj] = __builtin_amdgcn_mfma_f32_16x16x32_bf16(fa[ii], fb[jj], acc[ii][jj], 0, 0, 0);
    }
    __syncthreads();
  }

  if (grp < 2) {
    unsigned short* C = (grp == 0) ? C0 : C1;
#pragma unroll
    for (int ii = 0; ii < 4; ++ii)
#pragma unroll
      for (int jj = 0; jj < 4; ++jj)
#pragma unroll
        for (int r = 0; r < 4; ++r) {
          int row = m0 + wm * 64 + ii * 16 + l4 * 4 + r;
          int col = n0 + wn * 64 + jj * 16 + l15;
          C[(size_t)row * 512 + col] = f2bf(acc[ii][jj][r]);
        }
  } else {
    // transposed write: Vt[b][d][n]; tile rows are (b,n), cols are d
    int bb = m0 >> 9, nn0 = m0 & 511, d0 = n0;
#pragma unroll
    for (int p = 0; p < 2; ++p) {
      __syncthreads();
      if (wn == p) {
#pragma unroll
        for (int ii = 0; ii < 4; ++ii)
#pragma unroll
          for (int jj = 0; jj < 4; ++jj)
#pragma unroll
            for (int r = 0; r < 4; ++r) {
              int d = jj * 16 + l15;
              int m = wm * 64 + ii * 16 + l4 * 4 + r;
              *(unsigned short*)(lds + d * 272 + m * 2) = f2bf(acc[ii][jj][r]);
            }
      }
      __syncthreads();
      int dl = tid >> 2, seg = tid & 3;
      const char* sp = lds + dl * 272 + seg * 64;
      unsigned short* dp = C2 + (size_t)(bb * 512 + d0 + p * 64 + dl) * 512 + nn0 + seg * 32;
      *(u16x8*)(dp) = *(const u16x8*)(sp);
      *(u16x8*)(dp + 8) = *(const u16x8*)(sp + 16);
      *(u16x8*)(dp + 16) = *(const u16x8*)(sp + 32);
      *(u16x8*)(dp + 24) = *(const u16x8*)(sp + 48);
    }
  }
}

// ---------------- swapped-operand MHA: block=(b,h), 8 waves x 16 t-rows, no barriers ----------------
__global__ __launch_bounds__(512, 2)
void attn3_k(const unsigned short* __restrict__ Qb, const unsigned short* __restrict__ Kb,
             const unsigned short* __restrict__ Vt, const unsigned* __restrict__ mbits,
             unsigned short* __restrict__ mhaB) {
  int bid = blockIdx.x;
  int h = bid & 7, b = bid >> 3;
  int tid = threadIdx.x, lane = tid & 63, w = tid >> 6;
  int l15 = lane & 15, l4 = lane >> 4;
  int t = w * 16 + l15;                       // this lane's t (C-col)

  // masks: this t's 16 words
  unsigned mw[16];
  {
    const uint4* mp = (const uint4*)(mbits + (((size_t)b * 128 + t) << 4));
    uint4 a0 = mp[0], a1 = mp[1], a2 = mp[2], a3 = mp[3];
    mw[0] = a0.x; mw[1] = a0.y; mw[2] = a0.z; mw[3] = a0.w;
    mw[4] = a1.x; mw[5] = a1.y; mw[6] = a1.z; mw[7] = a1.w;
    mw[8] = a2.x; mw[9] = a2.y; mw[10] = a2.z; mw[11] = a2.w;
    mw[12] = a3.x; mw[13] = a3.y; mw[14] = a3.z; mw[15] = a3.w;
  }
  // Q B-frags (1/8 scale folded into Qb)
  bf16x8 fq[2];
#pragma unroll
  for (int ks = 0; ks < 2; ++ks)
    fq[ks] = *(const bf16x8*)(Qb + (size_t)(b * 128 + t) * 512 + h * 64 + ks * 32 + l4 * 8);

  // S^T = K Q^T: lane holds S[t][n] at n = jj*16 + l4*4 + r
  f32x4 s[32];
#pragma unroll
  for (int jj = 0; jj < 32; ++jj) s[jj] = (f32x4){0.f, 0.f, 0.f, 0.f};
#pragma unroll
  for (int jj = 0; jj < 32; ++jj) {
    const unsigned short* kp = Kb + (size_t)(b * 512 + jj * 16 + l15) * 512 + h * 64 + l4 * 8;
    bf16x8 k0 = *(const bf16x8*)(kp);
    bf16x8 k1 = *(const bf16x8*)(kp + 32);
    s[jj] = __builtin_amdgcn_mfma_f32_16x16x32_bf16(k0, fq[0], s[jj], 0, 0, 0);
    s[jj] = __builtin_amdgcn_mfma_f32_16x16x32_bf16(k1, fq[1], s[jj], 0, 0, 0);
  }

  // mask + row max (in-reg tree + 2 shfls)
  float mx = -3.0e38f;
#pragma unroll
  for (int jj = 0; jj < 32; ++jj) {
    unsigned nib = mw[jj >> 1] >> (((jj & 1) << 4) + (l4 << 2));
#pragma unroll
    for (int r = 0; r < 4; ++r)
      s[jj][r] = ((nib >> r) & 1) ? NEGF : s[jj][r];
    float m01 = fmaxf(s[jj][0], s[jj][1]);
    float m23 = fmaxf(s[jj][2], s[jj][3]);
    mx = fmaxf(mx, fmaxf(m01, m23));
  }
  mx = fmaxf(mx, __shfl_xor(mx, 16));
  mx = fmaxf(mx, __shfl_xor(mx, 32));

  // exp + sum
  float sum = 0.f;
#pragma unroll
  for (int jj = 0; jj < 32; ++jj) {
#pragma unroll
    for (int r = 0; r < 4; ++r) {
      float e = __expf(s[jj][r] - mx);
      s[jj][r] = e;
    }
    sum += (s[jj][0] + s[jj][1]) + (s[jj][2] + s[jj][3]);
  }
  sum += __shfl_xor(sum, 16);
  sum += __shfl_xor(sum, 32);
  float inv = 1.0f / sum;

  // PV: O^T = V^T P ; per 32-n block convert P^T(C-layout) -> B-frag via cvt_pk + shfl
  f32x4 o[4] = {};
  int src0 = l15 + ((l4 & 1) ? 32 : 0);
  int src2 = l15 + ((l4 & 1) ? 48 : 16);
  bool loh = (l4 < 2);
#pragma unroll
  for (int ks2 = 0; ks2 < 16; ++ks2) {
    unsigned a0 = cvtpk(s[2 * ks2][0], s[2 * ks2][1]);
    unsigned a1 = cvtpk(s[2 * ks2][2], s[2 * ks2][3]);
    unsigned b0 = cvtpk(s[2 * ks2 + 1][0], s[2 * ks2 + 1][1]);
    unsigned b1 = cvtpk(s[2 * ks2 + 1][2], s[2 * ks2 + 1][3]);
    unsigned wA0 = __shfl(a0, src0, 64), wB0 = __shfl(b0, src0, 64);
    unsigned wA1 = __shfl(a1, src0, 64), wB1 = __shfl(b1, src0, 64);
    unsigned wA2 = __shfl(a0, src2, 64), wB2 = __shfl(b0, src2, 64);
    unsigned wA3 = __shfl(a1, src2, 64), wB3 = __shfl(b1, src2, 64);
    union { unsigned u[4]; bf16x8 v; } pu;
    pu.u[0] = loh ? wA0 : wB0;
    pu.u[1] = loh ? wA1 : wB1;
    pu.u[2] = loh ? wA2 : wB2;
    pu.u[3] = loh ? wA3 : wB3;
#pragma unroll
    for (int dj = 0; dj < 4; ++dj) {
      bf16x8 fv = *(const bf16x8*)(Vt + (size_t)(b * 512 + h * 64 + dj * 16 + l15) * 512 + ks2 * 32 + l4 * 8);
      o[dj] = __builtin_amdgcn_mfma_f32_16x16x32_bf16(fv, pu.v, o[dj], 0, 0, 0);
    }
  }

  // normalize + write: O^T col=t(lane), row=d -> pack 4 consecutive d
#pragma unroll
  for (int dj = 0; dj < 4; ++dj) {
    ushort4 w4;
    w4.x = f2bf(o[dj][0] * inv);
    w4.y = f2bf(o[dj][1] * inv);
    w4.z = f2bf(o[dj][2] * inv);
    w4.w = f2bf(o[dj][3] * inv);
    *(ushort4*)(mhaB + (size_t)(b * 128 + t) * 512 + h * 64 + dj * 16 + l4 * 4) = w4;
  }
}

// ---------------- swapped pointer logits + tanh clip + masked softmax ----------------
__global__ __launch_bounds__(512, 2)
void comp3_k(const unsigned short* __restrict__ mhaO, const unsigned short* __restrict__ Ktb,
             const unsigned* __restrict__ mbits, float* __restrict__ out) {
  int b = blockIdx.x;
  int tid = threadIdx.x, lane = tid & 63, w = tid >> 6;
  int l15 = lane & 15, l4 = lane >> 4;
  int t = w * 16 + l15;

  unsigned mw[16];
  {
    const uint4* mp = (const uint4*)(mbits + (((size_t)b * 128 + t) << 4));
    uint4 a0 = mp[0], a1 = mp[1], a2 = mp[2], a3 = mp[3];
    mw[0] = a0.x; mw[1] = a0.y; mw[2] = a0.z; mw[3] = a0.w;
    mw[4] = a1.x; mw[5] = a1.y; mw[6] = a1.z; mw[7] = a1.w;
    mw[8] = a2.x; mw[9] = a2.y; mw[10] = a2.z; mw[11] = a2.w;
    mw[12] = a3.x; mw[13] = a3.y; mw[14] = a3.z; mw[15] = a3.w;
  }

  f32x4 s[32];
#pragma unroll
  for (int jj = 0; jj < 32; ++jj) s[jj] = (f32x4){0.f, 0.f, 0.f, 0.f};
  for (int ks = 0; ks < 16; ++ks) {
    bf16x8 fb = *(const bf16x8*)(mhaO + (size_t)(b * 128 + t) * 512 + ks * 32 + l4 * 8);
#pragma unroll
    for (int jj = 0; jj < 32; ++jj) {
      bf16x8 fa = *(const bf16x8*)(Ktb + (size_t)(b * 512 + jj * 16 + l15) * 512 + ks * 32 + l4 * 8);
      s[jj] = __builtin_amdgcn_mfma_f32_16x16x32_bf16(fa, fb, s[jj], 0, 0, 0);
    }
  }

  const float isd = 0.044194173824159216f;   // 1/sqrt(512)
  float sum = 0.f;
#pragma unroll
  for (int jj = 0; jj < 32; ++jj) {
    unsigned nib = mw[jj >> 1] >> (((jj & 1) << 4) + (l4 << 2));
#pragma unroll
    for (int r = 0; r < 4; ++r) {
      float y = s[jj][r] * isd;
      y = fminf(fmaxf(y, -15.f), 15.f);
      float e2 = __expf(2.f * y);
      float th = (e2 - 1.f) / (e2 + 1.f);
      float p = __expf(th * 10.f - 10.f);    // max(tanh*10)=10 -> exact softmax, no max pass
      p = ((nib >> r) & 1) ? 0.f : p;
      s[jj][r] = p;
      sum += p;
    }
  }
  sum += __shfl_xor(sum, 16);
  sum += __shfl_xor(sum, 32);
  float inv = 1.0f / sum;
#pragma unroll
  for (int jj = 0; jj < 32; ++jj) {
    float4 o4 = {s[jj][0] * inv, s[jj][1] * inv, s[jj][2] * inv, s[jj][3] * inv};
    *(float4*)(out + (size_t)(b * 128 + t) * 512 + jj * 16 + l4 * 4) = o4;
  }
}

extern "C" void kernel_launch(void* const* d_in, const int* in_sizes, int n_in,
                              void* d_out, int out_size, void* d_ws, size_t ws_size,
                              hipStream_t stream) {
  (void)in_sizes; (void)n_in; (void)out_size; (void)ws_size;
  const float* emb  = (const float*)d_in[0];
  const float* mge  = (const float*)d_in[1];
  const float* cap  = (const float*)d_in[2];
  const float* Wk   = (const float*)d_in[3];
  const float* Wkt  = (const float*)d_in[4];
  const float* Wv   = (const float*)d_in[5];
  const float* Wqc  = (const float*)d_in[6];
  const float* Wqs  = (const float*)d_in[7];
  const float* Wout = (const float*)d_in[8];
  const int* prev   = (const int*)d_in[9];
  const int* mask   = (const int*)d_in[10];
  float* out = (float*)d_out;

  char* p = (char*)d_ws;
  auto take = [&](size_t n) { char* q = p; p += (n + 255) & ~(size_t)255; return q; };
  unsigned short* embB = (unsigned short*)take((size_t)131072 * 512 * 2);
  unsigned short* Kb   = (unsigned short*)take((size_t)131072 * 512 * 2);
  unsigned short* Vt   = (unsigned short*)take((size_t)131072 * 512 * 2);
  unsigned short* Ktb  = (unsigned short*)take((size_t)131072 * 512 * 2);
  unsigned short* SCe  = (unsigned short*)take((size_t)32768 * 512 * 2);
  unsigned short* Qb   = (unsigned short*)take((size_t)32768 * 512 * 2);
  unsigned short* mhaB = (unsigned short*)take((size_t)32768 * 512 * 2);
  unsigned short* mhaO = (unsigned short*)take((size_t)32768 * 512 * 2);
  float*          Qc   = (float*)take((size_t)256 * 512 * 4);
  unsigned*       mbit = (unsigned*)take((size_t)256 * 128 * 16 * 4);
  unsigned short* WkT  = (unsigned short*)take(524288);
  unsigned short* WktT = (unsigned short*)take(524288);
  unsigned short* WvT  = (unsigned short*)take(524288);
  unsigned short* WqsT = (unsigned short*)take(524288);
  unsigned short* WoutT= (unsigned short*)take(524288);

  cast_emb_k<<<32768, 256, 0, stream>>>(emb, embB, 8388608);
  cast_wt_k<<<1280, 256, 0, stream>>>(Wk, Wkt, Wv, Wqs, Wout, WkT, WktT, WvT, WqsT, WoutT);
  qc_k<<<256, 256, 0, stream>>>(mge, Wqc, Qc);
  gather_k<<<8192, 256, 0, stream>>>(embB, prev, SCe);
  mbits_k<<<65536, 256, 0, stream>>>(mask, mbit);
  gemm5_k<3><<<1024, 256, 0, stream>>>(SCe, WqsT, Qb, Qc, Wqs + 512 * 512, cap);
  gemm5f_k<<<12288, 256, 0, stream>>>(embB, WkT, WktT, WvT, Kb, Ktb, Vt);
  attn3_k<<<2048, 512, 0, stream>>>(Qb, Kb, Vt, mbit, mhaB);
  gemm5_k<1><<<1024, 256, 0, stream>>>(mhaB, WoutT, mhaO, nullptr, nullptr, nullptr);
  comp3_k<<<256, 512, 0, stream>>>(mhaO, Ktb, mbit, out);
}

// Round 4
// 920.321 us; speedup vs baseline: 1.1372x; 1.0732x over previous
//
#include <hip/hip_runtime.h>
#include <hip/hip_bf16.h>

// Problem constants
constexpr int Bb = 256;   // batch
constexpr int Nn = 512;   // nodes
constexpr int Dd = 512;   // model dim
constexpr int Hh = 8;     // heads
constexpr int Tt = 128;   // steps
#define NEGF (-1.0e9f)

typedef __attribute__((ext_vector_type(4))) float f32x4;
typedef __attribute__((ext_vector_type(8))) short bf16x8;     // MFMA a/b frag (8 bf16)
typedef __attribute__((ext_vector_type(8))) unsigned short u16x8;

__device__ __forceinline__ unsigned short f2bf(float f) {
  union { float f; unsigned u; } v; v.f = f;
  unsigned r = v.u + 0x7fffu + ((v.u >> 16) & 1u);   // RNE
  return (unsigned short)(r >> 16);
}

__device__ __forceinline__ unsigned cvtpk(float lo, float hi) {
  unsigned r;
  asm("v_cvt_pk_bf16_f32 %0, %1, %2" : "=v"(r) : "v"(lo), "v"(hi));
  return r;
}

// ---------------- cast embeddings f32 -> bf16 ----------------
__global__ void cast_emb_k(const float* __restrict__ src, unsigned short* __restrict__ dst, int n8) {
  int i = blockIdx.x * 256 + threadIdx.x;
  if (i >= n8) return;
  const float4* s = (const float4*)src + (size_t)i * 2;
  float4 a = s[0], b = s[1];
  u16x8 o;
  o[0] = f2bf(a.x); o[1] = f2bf(a.y); o[2] = f2bf(a.z); o[3] = f2bf(a.w);
  o[4] = f2bf(b.x); o[5] = f2bf(b.y); o[6] = f2bf(b.z); o[7] = f2bf(b.w);
  ((u16x8*)dst)[i] = o;
}

// ---------------- transpose-cast 512x512 weight blocks to [n][k] bf16 ----------------
__global__ void cast_wt_k(const float* __restrict__ W0, const float* __restrict__ W1,
                          const float* __restrict__ W2, const float* __restrict__ W3,
                          const float* __restrict__ W4,
                          unsigned short* __restrict__ D0, unsigned short* __restrict__ D1,
                          unsigned short* __restrict__ D2, unsigned short* __restrict__ D3,
                          unsigned short* __restrict__ D4) {
  int mid = blockIdx.x >> 8;
  int tile = blockIdx.x & 255;
  const float* S = (mid == 0) ? W0 : (mid == 1) ? W1 : (mid == 2) ? W2 : (mid == 3) ? W3 : W4;
  unsigned short* Dst = (mid == 0) ? D0 : (mid == 1) ? D1 : (mid == 2) ? D2 : (mid == 3) ? D3 : D4;
  __shared__ float t[32][33];
  int r0 = (tile >> 4) * 32, c0 = (tile & 15) * 32;
  int tx = threadIdx.x & 31, ty = threadIdx.x >> 5;
#pragma unroll
  for (int yy = 0; yy < 4; ++yy) {
    int r = ty + yy * 8;
    t[r][tx] = S[(size_t)(r0 + r) * 512 + c0 + tx];
  }
  __syncthreads();
#pragma unroll
  for (int yy = 0; yy < 4; ++yy) {
    int c = ty + yy * 8;
    Dst[(size_t)(c0 + c) * 512 + r0 + tx] = f2bf(t[tx][c]);   // Dst[n][k] = W[k][n]
  }
}

// ---------------- Q_context = mge @ Wqc (f32) ----------------
__global__ void qc_k(const float* __restrict__ mge, const float* __restrict__ Wqc,
                     float* __restrict__ Qc) {
  int b = blockIdx.x;
  __shared__ float m[512];
  m[threadIdx.x] = mge[(size_t)b * 512 + threadIdx.x];
  m[threadIdx.x + 256] = mge[(size_t)b * 512 + threadIdx.x + 256];
  __syncthreads();
  float a0 = 0.f, a1 = 0.f;
  for (int k = 0; k < 512; ++k) {
    float mk = m[k];
    a0 += mk * Wqc[(size_t)k * 512 + threadIdx.x];
    a1 += mk * Wqc[(size_t)k * 512 + threadIdx.x + 256];
  }
  Qc[(size_t)b * 512 + threadIdx.x] = a0;
  Qc[(size_t)b * 512 + threadIdx.x + 256] = a1;
}

// ---------------- gather step-context rows (bf16) ----------------
__global__ void gather_k(const unsigned short* __restrict__ embB, const int* __restrict__ prev,
                         unsigned short* __restrict__ SC) {
  int row = blockIdx.x * 4 + (threadIdx.x >> 6);   // row = t*B + b
  int lane = threadIdx.x & 63;
  int t = row >> 8, b = row & 255;
  int pa = prev[t * Bb + b];
  const u16x8* s = (const u16x8*)(embB + (size_t)(b * 512 + pa) * 512) + lane;
  *((u16x8*)(SC + (size_t)row * 512) + lane) = *s;
}

// ---------------- mask -> bitmask  bits[b][t][16 words] ----------------
__global__ void mbits_k(const int* __restrict__ mask, unsigned* __restrict__ bits) {
  size_t gid = (size_t)blockIdx.x * 256 + threadIdx.x;   // element over T*B*N
  int mv = mask[gid];
  unsigned long long bal = __ballot(mv == 1);
  if ((threadIdx.x & 63) == 0) {
    unsigned t = (unsigned)(gid >> 17);
    unsigned b = (unsigned)((gid >> 9) & 255);
    unsigned n = (unsigned)(gid & 511);
    unsigned* dst = bits + (((size_t)b * 128 + t) * 16 + (n >> 5));
    dst[0] = (unsigned)bal;
    dst[1] = (unsigned)(bal >> 32);
  }
}

// ---------------- shared staging: 128x64 bf16 tile via global_load_lds (16B) ----------------
__device__ __forceinline__ void stage_tile(const unsigned short* __restrict__ G, int row0, int k0,
                                           unsigned short* lds_base, int wave, int lane) {
#pragma unroll
  for (int c = 0; c < 4; ++c) {
    int chunk = wave * 4 + c;                       // 16 chunks of 1KB (8 rows each)
    const unsigned short* g = G + (size_t)(row0 + chunk * 8 + (lane >> 3)) * 512 + k0 + (lane & 7) * 8;
    __builtin_amdgcn_global_load_lds((__attribute__((address_space(1))) void*)g,
                                     (__attribute__((address_space(3))) void*)(lds_base + chunk * 512),
                                     16, 0, 0);
  }
}

// ---------------- small GEMM (m97 2-phase): C[M,512] = A[M,512] x BT^T, M=32768 ----------------
// MODE 1: bf16 out; MODE 3: q-epilogue.
template <int MODE>
__global__ __launch_bounds__(256, 2)
void gemm5_k(const unsigned short* __restrict__ A, const unsigned short* __restrict__ BT,
             void* __restrict__ Cout,
             const float* __restrict__ Qc, const float* __restrict__ WqsL,
             const float* __restrict__ capp) {
  __shared__ __align__(16) char lds[32768];
  unsigned short* ldsA = (unsigned short*)lds;
  unsigned short* ldsB = ldsA + 8192;
  int xcd = blockIdx.x & 7, loc = blockIdx.x >> 3;
  int ml = loc >> 2, nt = loc & 3;
  int mt = xcd * 32 + ml;
  int m0 = mt * 128, n0 = nt * 128;
  int tid = threadIdx.x, lane = tid & 63, w = tid >> 6;
  int wm = w >> 1, wn = w & 1;
  int l15 = lane & 15, l4 = lane >> 4;

  f32x4 acc[4][4] = {};
  for (int k0 = 0; k0 < 512; k0 += 64) {
    stage_tile(A, m0, k0, ldsA, w, lane);
    stage_tile(BT, n0, k0, ldsB, w, lane);
    __syncthreads();
#pragma unroll
    for (int ks = 0; ks < 2; ++ks) {
      bf16x8 fa[4], fb[4];
#pragma unroll
      for (int ii = 0; ii < 4; ++ii)
        fa[ii] = *(const bf16x8*)(ldsA + (wm * 64 + ii * 16 + l15) * 64 + ks * 32 + l4 * 8);
#pragma unroll
      for (int jj = 0; jj < 4; ++jj)
        fb[jj] = *(const bf16x8*)(ldsB + (wn * 64 + jj * 16 + l15) * 64 + ks * 32 + l4 * 8);
#pragma unroll
      for (int ii = 0; ii < 4; ++ii)
#pragma unroll
        for (int jj = 0; jj < 4; ++jj)
          acc[ii][jj] = __builtin_amdgcn_mfma_f32_16x16x32_bf16(fa[ii], fb[jj], acc[ii][jj], 0, 0, 0);
    }
    __syncthreads();
  }

  if (MODE == 1) {
    unsigned short* C = (unsigned short*)Cout;
#pragma unroll
    for (int ii = 0; ii < 4; ++ii)
#pragma unroll
      for (int jj = 0; jj < 4; ++jj)
#pragma unroll
        for (int r = 0; r < 4; ++r) {
          int row = m0 + wm * 64 + ii * 16 + l4 * 4 + r;
          int col = n0 + wn * 64 + jj * 16 + l15;
          C[(size_t)row * 512 + col] = f2bf(acc[ii][jj][r]);
        }
  } else {
    // MODE 3: rows m = t*256 + b; write Qb[(b*128+t)*512+col] = bf16((acc+Qc+(1-cap)*WqsL)/8)
    unsigned short* C = (unsigned short*)Cout;
#pragma unroll
    for (int ii = 0; ii < 4; ++ii)
#pragma unroll
      for (int jj = 0; jj < 4; ++jj)
#pragma unroll
        for (int r = 0; r < 4; ++r) {
          int row = m0 + wm * 64 + ii * 16 + l4 * 4 + r;
          int col = n0 + wn * 64 + jj * 16 + l15;
          int t = row >> 8, bbx = row & 255;
          float val = acc[ii][jj][r] + Qc[(size_t)bbx * 512 + col] + (1.0f - capp[row]) * WqsL[col];
          C[(size_t)(bbx * 128 + t) * 512 + col] = f2bf(val * 0.125f);
        }
  }
}

// ================= 256x256 8-phase fused triple GEMM (T2+T3+T4+T5) =================
// embB[131072][512] x {WkT,WktT,WvT}[512][512]^T -> C0=Kb, C1=Ktb (bf16 [row][512]),
// C2=Vt (bf16 transposed [b][d][n]).
// LDS: slot s(2) x mat(A,B) x half(2) x [128 rows][64 k] bf16, swizzle c^=(r&7)<<4.

#define STAGE8(SLOT, MAT, H, KT)                                                   \
  do {                                                                             \
    const unsigned short* G_ = (MAT) ? BT : A;                                     \
    int rb_ = ((MAT) ? n0 : m0) + (H) * 128;                                       \
    char* Lb_ = lds + (SLOT) * 65536 + (MAT) * 32768 + (H) * 16384;                \
    _Pragma("unroll")                                                              \
    for (int sh_ = 0; sh_ < 2; ++sh_) {                                            \
      int off_ = sh_ * 8192 + tid * 16;                                            \
      int r_ = off_ >> 7;                                                          \
      int c_ = (off_ & 127) ^ ((r_ & 7) << 4);   /* pre-swizzled global source */  \
      const char* g_ = (const char*)(G_ + (size_t)(rb_ + r_) * 512 + (KT) * 64) + c_; \
      __builtin_amdgcn_global_load_lds((__attribute__((address_space(1))) void*)g_, \
          (__attribute__((address_space(3))) void*)(Lb_ + off_), 16, 0, 0);        \
    }                                                                              \
  } while (0)

#define LDA_Q(QM)                                                   \
  _Pragma("unroll")                                                 \
  for (int ii = 0; ii < 4; ++ii) {                                  \
    int rr_ = (QM) * 64 + ii * 16 + l15;                            \
    const char* ap_ = ldsAh + rr_ * 128;                            \
    int sw_ = (rr_ & 7) << 4;                                       \
    fa[ii][0] = *(const bf16x8*)(ap_ + ((l4 * 16) ^ sw_));          \
    fa[ii][1] = *(const bf16x8*)(ap_ + ((64 + l4 * 16) ^ sw_));     \
  }

#define LDB_Q(QN)                                                   \
  _Pragma("unroll")                                                 \
  for (int jj = 0; jj < 2; ++jj) {                                  \
    int rr_ = (wn & 1) * 64 + (QN) * 32 + jj * 16 + l15;            \
    const char* bp_ = ldsBh + rr_ * 128;                            \
    int sw_ = (rr_ & 7) << 4;                                       \
    fb[jj][0] = *(const bf16x8*)(bp_ + ((l4 * 16) ^ sw_));          \
    fb[jj][1] = *(const bf16x8*)(bp_ + ((64 + l4 * 16) ^ sw_));     \
  }

#define MM16(QM, QN)                                                              \
  do {                                                                            \
    __builtin_amdgcn_s_setprio(1);                                                \
    _Pragma("unroll")                                                             \
    for (int ii = 0; ii < 4; ++ii)                                                \
      _Pragma("unroll")                                                           \
      for (int jj = 0; jj < 2; ++jj) {                                            \
        acc[(QM) * 4 + ii][(QN) * 2 + jj] = __builtin_amdgcn_mfma_f32_16x16x32_bf16( \
            fa[ii][0], fb[jj][0], acc[(QM) * 4 + ii][(QN) * 2 + jj], 0, 0, 0);    \
        acc[(QM) * 4 + ii][(QN) * 2 + jj] = __builtin_amdgcn_mfma_f32_16x16x32_bf16( \
            fa[ii][1], fb[jj][1], acc[(QM) * 4 + ii][(QN) * 2 + jj], 0, 0, 0);    \
      }                                                                           \
    __builtin_amdgcn_s_setprio(0);                                                \
  } while (0)

__global__ __launch_bounds__(512, 1)
void gemm8f_k(const unsigned short* __restrict__ A,
              const unsigned short* __restrict__ B0, const unsigned short* __restrict__ B1,
              const unsigned short* __restrict__ B2,
              unsigned short* __restrict__ C0, unsigned short* __restrict__ C1,
              unsigned short* __restrict__ C2) {
  __shared__ __align__(16) char lds[131072];
  int xcd = blockIdx.x & 7, loc = blockIdx.x >> 3;   // loc < 384
  int ml = loc / 6, cmb = loc - ml * 6;              // 6 (weight,nhalf) combos share A-tile via L2
  int grp = cmb >> 1, nh = cmb & 1;
  const unsigned short* BT = (grp == 0) ? B0 : (grp == 1) ? B1 : B2;
  int mt = xcd * 64 + ml;
  int m0 = mt * 256;            // A rows
  int n0 = nh * 256;            // B rows (output cols)
  int tid = threadIdx.x, lane = tid & 63, w = tid >> 6;
  int wm = w >> 2, wn = w & 3;  // 2 x 4 waves; per-wave output 128m x 64n
  int l15 = lane & 15, l4 = lane >> 4;

  f32x4 acc[8][4] = {};
  bf16x8 fa[4][2], fb[2][2];

  // prologue: stage K-tile 0 into slot 0 (8 loads/thread)
  STAGE8(0, 0, 0, 0); STAGE8(0, 0, 1, 0); STAGE8(0, 1, 0, 0); STAGE8(0, 1, 1, 0);

  for (int kt = 0; kt < 8; ++kt) {
    int s = kt & 1, sn = s ^ 1;
    char* ldsAh = lds + s * 65536 + wm * 16384;
    char* ldsBh = lds + s * 65536 + 32768 + (wn >> 1) * 16384;
    // ---- phase 0: stage h0A(kt+1); counted vmcnt; quadrant (0,0)
    if (kt < 7) {
      STAGE8(sn, 0, 0, kt + 1);
      asm volatile("s_waitcnt vmcnt(2)" ::: "memory");
    } else {
      asm volatile("s_waitcnt vmcnt(0)" ::: "memory");
    }
    __builtin_amdgcn_s_barrier();
    LDA_Q(0); LDB_Q(0);
    MM16(0, 0);
    __builtin_amdgcn_s_barrier();
    // ---- phase 1: quadrant (0,1)
    LDB_Q(1);
    if (kt < 7) STAGE8(sn, 0, 1, kt + 1);
    __builtin_amdgcn_s_barrier();
    MM16(0, 1);
    __builtin_amdgcn_s_barrier();
    // ---- phase 2: quadrant (1,1)
    LDA_Q(1);
    if (kt < 7) STAGE8(sn, 1, 0, kt + 1);
    __builtin_amdgcn_s_barrier();
    MM16(1, 1);
    __builtin_amdgcn_s_barrier();
    // ---- phase 3: quadrant (1,0)
    LDB_Q(0);
    if (kt < 7) STAGE8(sn, 1, 1, kt + 1);
    __builtin_amdgcn_s_barrier();
    MM16(1, 0);
    __builtin_amdgcn_s_barrier();
  }

  if (grp < 2) {
    unsigned short* C = (grp == 0) ? C0 : C1;
#pragma unroll
    for (int mi = 0; mi < 8; ++mi)
#pragma unroll
      for (int nj = 0; nj < 4; ++nj)
#pragma unroll
        for (int r = 0; r < 4; ++r) {
          int row = m0 + wm * 128 + mi * 16 + l4 * 4 + r;
          int col = n0 + wn * 64 + nj * 16 + l15;
          C[(size_t)row * 512 + col] = f2bf(acc[mi][nj][r]);
        }
  } else {
    // V: transposed write Vt[b][d][n] via per-wave-private LDS bounce (no barriers needed)
    int bb = m0 >> 9, nn0 = m0 & 511;
    char* wlds = lds + w * 16384;          // 8.5KB used of 16KB per wave
#pragma unroll
    for (int p = 0; p < 2; ++p) {          // 32 d-cols per pass
#pragma unroll
      for (int njl = 0; njl < 2; ++njl) {
        int nj = p * 2 + njl;
#pragma unroll
        for (int mi = 0; mi < 8; ++mi) {
          ushort4 w4;
          w4.x = f2bf(acc[mi][nj][0]);
          w4.y = f2bf(acc[mi][nj][1]);
          w4.z = f2bf(acc[mi][nj][2]);
          w4.w = f2bf(acc[mi][nj][3]);
          int dc = njl * 16 + l15;
          int nl = mi * 16 + l4 * 4;
          *(ushort4*)(wlds + dc * 272 + nl * 2) = w4;
        }
      }
#pragma unroll
      for (int rr = 0; rr < 8; ++rr) {
        int dc = rr * 4 + l4;
        int n8 = l15 * 8;
        u16x8 v = *(const u16x8*)(wlds + dc * 272 + n8 * 2);
        int dglob = n0 + wn * 64 + p * 32 + dc;
        *(u16x8*)(C2 + (size_t)(bb * 512 + dglob) * 512 + nn0 + wm * 128 + n8) = v;
      }
    }
  }
}

// ---------------- swapped-operand MHA: block=(b,h), 8 waves x 16 t-rows, no barriers ----------------
__global__ __launch_bounds__(512, 2)
void attn3_k(const unsigned short* __restrict__ Qb, const unsigned short* __restrict__ Kb,
             const unsigned short* __restrict__ Vt, const unsigned* __restrict__ mbits,
             unsigned short* __restrict__ mhaB) {
  int bid = blockIdx.x;
  int h = bid & 7, b = bid >> 3;
  int tid = threadIdx.x, lane = tid & 63, w = tid >> 6;
  int l15 = lane & 15, l4 = lane >> 4;
  int t = w * 16 + l15;                       // this lane's t (C-col)

  // masks: this t's 16 words
  unsigned mw[16];
  {
    const uint4* mp = (const uint4*)(mbits + (((size_t)b * 128 + t) << 4));
    uint4 a0 = mp[0], a1 = mp[1], a2 = mp[2], a3 = mp[3];
    mw[0] = a0.x; mw[1] = a0.y; mw[2] = a0.z; mw[3] = a0.w;
    mw[4] = a1.x; mw[5] = a1.y; mw[6] = a1.z; mw[7] = a1.w;
    mw[8] = a2.x; mw[9] = a2.y; mw[10] = a2.z; mw[11] = a2.w;
    mw[12] = a3.x; mw[13] = a3.y; mw[14] = a3.z; mw[15] = a3.w;
  }
  // Q B-frags (1/8 scale folded into Qb)
  bf16x8 fq[2];
#pragma unroll
  for (int ks = 0; ks < 2; ++ks)
    fq[ks] = *(const bf16x8*)(Qb + (size_t)(b * 128 + t) * 512 + h * 64 + ks * 32 + l4 * 8);

  // S^T = K Q^T: lane holds S[t][n] at n = jj*16 + l4*4 + r
  f32x4 s[32];
#pragma unroll
  for (int jj = 0; jj < 32; ++jj) s[jj] = (f32x4){0.f, 0.f, 0.f, 0.f};
#pragma unroll
  for (int jj = 0; jj < 32; ++jj) {
    const unsigned short* kp = Kb + (size_t)(b * 512 + jj * 16 + l15) * 512 + h * 64 + l4 * 8;
    bf16x8 k0 = *(const bf16x8*)(kp);
    bf16x8 k1 = *(const bf16x8*)(kp + 32);
    s[jj] = __builtin_amdgcn_mfma_f32_16x16x32_bf16(k0, fq[0], s[jj], 0, 0, 0);
    s[jj] = __builtin_amdgcn_mfma_f32_16x16x32_bf16(k1, fq[1], s[jj], 0, 0, 0);
  }

  // mask + row max (in-reg tree + 2 shfls)
  float mx = -3.0e38f;
#pragma unroll
  for (int jj = 0; jj < 32; ++jj) {
    unsigned nib = mw[jj >> 1] >> (((jj & 1) << 4) + (l4 << 2));
#pragma unroll
    for (int r = 0; r < 4; ++r)
      s[jj][r] = ((nib >> r) & 1) ? NEGF : s[jj][r];
    float m01 = fmaxf(s[jj][0], s[jj][1]);
    float m23 = fmaxf(s[jj][2], s[jj][3]);
    mx = fmaxf(mx, fmaxf(m01, m23));
  }
  mx = fmaxf(mx, __shfl_xor(mx, 16));
  mx = fmaxf(mx, __shfl_xor(mx, 32));

  // exp + sum
  float sum = 0.f;
#pragma unroll
  for (int jj = 0; jj < 32; ++jj) {
#pragma unroll
    for (int r = 0; r < 4; ++r) {
      float e = __expf(s[jj][r] - mx);
      s[jj][r] = e;
    }
    sum += (s[jj][0] + s[jj][1]) + (s[jj][2] + s[jj][3]);
  }
  sum += __shfl_xor(sum, 16);
  sum += __shfl_xor(sum, 32);
  float inv = 1.0f / sum;

  // PV: O^T = V^T P ; per 32-n block convert P^T(C-layout) -> B-frag via cvt_pk + shfl
  f32x4 o[4] = {};
  int src0 = l15 + ((l4 & 1) ? 32 : 0);
  int src2 = l15 + ((l4 & 1) ? 48 : 16);
  bool loh = (l4 < 2);
#pragma unroll
  for (int ks2 = 0; ks2 < 16; ++ks2) {
    unsigned a0 = cvtpk(s[2 * ks2][0], s[2 * ks2][1]);
    unsigned a1 = cvtpk(s[2 * ks2][2], s[2 * ks2][3]);
    unsigned b0 = cvtpk(s[2 * ks2 + 1][0], s[2 * ks2 + 1][1]);
    unsigned b1 = cvtpk(s[2 * ks2 + 1][2], s[2 * ks2 + 1][3]);
    unsigned wA0 = __shfl(a0, src0, 64), wB0 = __shfl(b0, src0, 64);
    unsigned wA1 = __shfl(a1, src0, 64), wB1 = __shfl(b1, src0, 64);
    unsigned wA2 = __shfl(a0, src2, 64), wB2 = __shfl(b0, src2, 64);
    unsigned wA3 = __shfl(a1, src2, 64), wB3 = __shfl(b1, src2, 64);
    union { unsigned u[4]; bf16x8 v; } pu;
    pu.u[0] = loh ? wA0 : wB0;
    pu.u[1] = loh ? wA1 : wB1;
    pu.u[2] = loh ? wA2 : wB2;
    pu.u[3] = loh ? wA3 : wB3;
#pragma unroll
    for (int dj = 0; dj < 4; ++dj) {
      bf16x8 fv = *(const bf16x8*)(Vt + (size_t)(b * 512 + h * 64 + dj * 16 + l15) * 512 + ks2 * 32 + l4 * 8);
      o[dj] = __builtin_amdgcn_mfma_f32_16x16x32_bf16(fv, pu.v, o[dj], 0, 0, 0);
    }
  }

  // normalize + write: O^T col=t(lane), row=d -> pack 4 consecutive d
#pragma unroll
  for (int dj = 0; dj < 4; ++dj) {
    ushort4 w4;
    w4.x = f2bf(o[dj][0] * inv);
    w4.y = f2bf(o[dj][1] * inv);
    w4.z = f2bf(o[dj][2] * inv);
    w4.w = f2bf(o[dj][3] * inv);
    *(ushort4*)(mhaB + (size_t)(b * 128 + t) * 512 + h * 64 + dj * 16 + l4 * 4) = w4;
  }
}

// ---------------- swapped pointer logits + tanh clip + masked softmax ----------------
__global__ __launch_bounds__(512, 2)
void comp3_k(const unsigned short* __restrict__ mhaO, const unsigned short* __restrict__ Ktb,
             const unsigned* __restrict__ mbits, float* __restrict__ out) {
  int b = blockIdx.x;
  int tid = threadIdx.x, lane = tid & 63, w = tid >> 6;
  int l15 = lane & 15, l4 = lane >> 4;
  int t = w * 16 + l15;

  unsigned mw[16];
  {
    const uint4* mp = (const uint4*)(mbits + (((size_t)b * 128 + t) << 4));
    uint4 a0 = mp[0], a1 = mp[1], a2 = mp[2], a3 = mp[3];
    mw[0] = a0.x; mw[1] = a0.y; mw[2] = a0.z; mw[3] = a0.w;
    mw[4] = a1.x; mw[5] = a1.y; mw[6] = a1.z; mw[7] = a1.w;
    mw[8] = a2.x; mw[9] = a2.y; mw[10] = a2.z; mw[11] = a2.w;
    mw[12] = a3.x; mw[13] = a3.y; mw[14] = a3.z; mw[15] = a3.w;
  }

  f32x4 s[32];
#pragma unroll
  for (int jj = 0; jj < 32; ++jj) s[jj] = (f32x4){0.f, 0.f, 0.f, 0.f};
  for (int ks = 0; ks < 16; ++ks) {
    bf16x8 fb = *(const bf16x8*)(mhaO + (size_t)(b * 128 + t) * 512 + ks * 32 + l4 * 8);
#pragma unroll
    for (int jj = 0; jj < 32; ++jj) {
      bf16x8 fa = *(const bf16x8*)(Ktb + (size_t)(b * 512 + jj * 16 + l15) * 512 + ks * 32 + l4 * 8);
      s[jj] = __builtin_amdgcn_mfma_f32_16x16x32_bf16(fa, fb, s[jj], 0, 0, 0);
    }
  }

  const float isd = 0.044194173824159216f;   // 1/sqrt(512)
  float sum = 0.f;
#pragma unroll
  for (int jj = 0; jj < 32; ++jj) {
    unsigned nib = mw[jj >> 1] >> (((jj & 1) << 4) + (l4 << 2));
#pragma unroll
    for (int r = 0; r < 4; ++r) {
      float y = s[jj][r] * isd;
      y = fminf(fmaxf(y, -15.f), 15.f);
      float e2 = __expf(2.f * y);
      float th = (e2 - 1.f) / (e2 + 1.f);
      float p = __expf(th * 10.f - 10.f);    // max(tanh*10)=10 -> exact softmax, no max pass
      p = ((nib >> r) & 1) ? 0.f : p;
      s[jj][r] = p;
      sum += p;
    }
  }
  sum += __shfl_xor(sum, 16);
  sum += __shfl_xor(sum, 32);
  float inv = 1.0f / sum;
#pragma unroll
  for (int jj = 0; jj < 32; ++jj) {
    float4 o4 = {s[jj][0] * inv, s[jj][1] * inv, s[jj][2] * inv, s[jj][3] * inv};
    *(float4*)(out + (size_t)(b * 128 + t) * 512 + jj * 16 + l4 * 4) = o4;
  }
}

extern "C" void kernel_launch(void* const* d_in, const int* in_sizes, int n_in,
                              void* d_out, int out_size, void* d_ws, size_t ws_size,
                              hipStream_t stream) {
  (void)in_sizes; (void)n_in; (void)out_size; (void)ws_size;
  const float* emb  = (const float*)d_in[0];
  const float* mge  = (const float*)d_in[1];
  const float* cap  = (const float*)d_in[2];
  const float* Wk   = (const float*)d_in[3];
  const float* Wkt  = (const float*)d_in[4];
  const float* Wv   = (const float*)d_in[5];
  const float* Wqc  = (const float*)d_in[6];
  const float* Wqs  = (const float*)d_in[7];
  const float* Wout = (const float*)d_in[8];
  const int* prev   = (const int*)d_in[9];
  const int* mask   = (const int*)d_in[10];
  float* out = (float*)d_out;

  char* p = (char*)d_ws;
  auto take = [&](size_t n) { char* q = p; p += (n + 255) & ~(size_t)255; return q; };
  unsigned short* embB = (unsigned short*)take((size_t)131072 * 512 * 2);
  unsigned short* Kb   = (unsigned short*)take((size_t)131072 * 512 * 2);
  unsigned short* Vt   = (unsigned short*)take((size_t)131072 * 512 * 2);
  unsigned short* Ktb  = (unsigned short*)take((size_t)131072 * 512 * 2);
  unsigned short* SCe  = (unsigned short*)take((size_t)32768 * 512 * 2);
  unsigned short* Qb   = (unsigned short*)take((size_t)32768 * 512 * 2);
  unsigned short* mhaB = (unsigned short*)take((size_t)32768 * 512 * 2);
  unsigned short* mhaO = (unsigned short*)take((size_t)32768 * 512 * 2);
  float*          Qc   = (float*)take((size_t)256 * 512 * 4);
  unsigned*       mbit = (unsigned*)take((size_t)256 * 128 * 16 * 4);
  unsigned short* WkT  = (unsigned short*)take(524288);
  unsigned short* WktT = (unsigned short*)take(524288);
  unsigned short* WvT  = (unsigned short*)take(524288);
  unsigned short* WqsT = (unsigned short*)take(524288);
  unsigned short* WoutT= (unsigned short*)take(524288);

  cast_emb_k<<<32768, 256, 0, stream>>>(emb, embB, 8388608);
  cast_wt_k<<<1280, 256, 0, stream>>>(Wk, Wkt, Wv, Wqs, Wout, WkT, WktT, WvT, WqsT, WoutT);
  qc_k<<<256, 256, 0, stream>>>(mge, Wqc, Qc);
  gather_k<<<8192, 256, 0, stream>>>(embB, prev, SCe);
  mbits_k<<<65536, 256, 0, stream>>>(mask, mbit);
  gemm5_k<3><<<1024, 256, 0, stream>>>(SCe, WqsT, Qb, Qc, Wqs + 512 * 512, cap);
  gemm8f_k<<<3072, 512, 0, stream>>>(embB, WkT, WktT, WvT, Kb, Ktb, Vt);
  attn3_k<<<2048, 512, 0, stream>>>(Qb, Kb, Vt, mbit, mhaB);
  gemm5_k<1><<<1024, 256, 0, stream>>>(mhaB, WoutT, mhaO, nullptr, nullptr, nullptr);
  comp3_k<<<256, 512, 0, stream>>>(mhaO, Ktb, mbit, out);
}